// Round 1
// 2747.934 us; speedup vs baseline: 1.7326x; 1.7326x over previous
//
#include <hip/hip_runtime.h>
#include <hip/hip_bf16.h>
#include <math.h>

#define HID 4096
#define NH 32
#define HD 128
#define SEQ 2048
#define NKT 64
#define HHSZ 256
#define RECENT 512
#define CACHE 768
#define SELN 1536
#define RSQRT_D 0.08838834764831845f

typedef unsigned short ushortT;
typedef __attribute__((ext_vector_type(8))) short short8;
typedef __attribute__((ext_vector_type(4))) float f32x4;

// ================= bf16 split helpers =====================================
__device__ __forceinline__ ushortT f2b(float f) {
  union { __hip_bfloat16 h; ushortT u; } v;
  v.h = __float2bfloat16(f);
  return v.u;
}
__device__ __forceinline__ float b2f(ushortT u) {
  union { unsigned int i; float f; } v;
  v.i = ((unsigned int)u) << 16;
  return v.f;
}
__device__ __forceinline__ void split3(float x, ushortT& h, ushortT& m, ushortT& l) {
  h = f2b(x);
  float r = x - b2f(h);
  m = f2b(r);
  float r2 = r - b2f(m);
  l = f2b(r2);
}
__device__ __forceinline__ void split2(float x, ushortT& h, ushortT& l) {
  h = f2b(x);
  l = f2b(x - b2f(h));
}

__global__ __launch_bounds__(256) void split3_kernel(const float* __restrict__ X,
    ushortT* __restrict__ o0, ushortT* __restrict__ o1, ushortT* __restrict__ o2, int n4) {
  int i = blockIdx.x * 256 + threadIdx.x;
  if (i >= n4) return;
  float4 x = ((const float4*)X)[i];
  ushort4 a, b, c;
  split3(x.x, a.x, b.x, c.x);
  split3(x.y, a.y, b.y, c.y);
  split3(x.z, a.z, b.z, c.z);
  split3(x.w, a.w, b.w, c.w);
  ((ushort4*)o0)[i] = a;
  ((ushort4*)o1)[i] = b;
  ((ushort4*)o2)[i] = c;
}
__global__ __launch_bounds__(256) void split2_kernel(const float* __restrict__ X,
    ushortT* __restrict__ o0, ushortT* __restrict__ o1, int n4) {
  int i = blockIdx.x * 256 + threadIdx.x;
  if (i >= n4) return;
  float4 x = ((const float4*)X)[i];
  ushort4 a, b;
  split2(x.x, a.x, b.x);
  split2(x.y, a.y, b.y);
  split2(x.z, a.z, b.z);
  split2(x.w, a.w, b.w);
  ((ushort4*)o0)[i] = a;
  ((ushort4*)o1)[i] = b;
}

// split V [h][s][128] fp32 -> transposed bf16 levels [h][128][2048]
__global__ __launch_bounds__(256) void split2t_kernel(const float* __restrict__ V,
    ushortT* __restrict__ oH, ushortT* __restrict__ oL) {
  __shared__ float T[32][33];
  const int h = blockIdx.z, s0 = blockIdx.x * 32, d0 = blockIdx.y * 32;
  const int t = threadIdx.x;
  {
    int sr = t >> 3, dc = (t & 7) * 4;
    float4 v = *(const float4*)&V[(((size_t)h * SEQ + s0 + sr) << 7) + d0 + dc];
    T[sr][dc + 0] = v.x; T[sr][dc + 1] = v.y;
    T[sr][dc + 2] = v.z; T[sr][dc + 3] = v.w;
  }
  __syncthreads();
  int dr = t >> 3, sc = (t & 7) * 4;
  ushort4 a, b;
  split2(T[sc + 0][dr], a.x, b.x);
  split2(T[sc + 1][dr], a.y, b.y);
  split2(T[sc + 2][dr], a.z, b.z);
  split2(T[sc + 3][dr], a.w, b.w);
  size_t dst = ((size_t)h * HD + d0 + dr) * SEQ + s0 + sc;
  *(ushort4*)&oH[dst] = a;
  *(ushort4*)&oL[dst] = b;
}

// ================= async global->LDS ======================================
__device__ __forceinline__ void gload16(const void* g, void* lds) {
  __builtin_amdgcn_global_load_lds(
      (const __attribute__((address_space(1))) unsigned int*)g,
      (__attribute__((address_space(3))) unsigned int*)lds, 16, 0, 0);
}

__device__ __forceinline__ f32x4 mfma16(short8 a, short8 b, f32x4 c) {
  return __builtin_amdgcn_mfma_f32_16x16x32_bf16(a, b, c, 0, 0, 0);
}

// ================= split-bf16 MFMA GEMM  C = A * B^T ======================
template<int LEV, int MODE>
__global__ __launch_bounds__(256, 2) void gemm_mfma(
    const ushortT* __restrict__ A0, const ushortT* __restrict__ A1, const ushortT* __restrict__ A2,
    const ushortT* __restrict__ B0, const ushortT* __restrict__ B1, const ushortT* __restrict__ B2,
    float* __restrict__ C) {
  __shared__ ushortT As[LEV][4096];
  __shared__ ushortT Bs[LEV][4096];
  const int tid = threadIdx.x;
  const int w = tid >> 6, l = tid & 63;
  const int m16 = l & 15, quad = l >> 4;
  const int wr = w >> 1, wc = w & 1;
  const int m0 = blockIdx.y * 128, n0 = blockIdx.x * 128;
  const ushortT* Aarr[3] = {A0, A1, A2};
  const ushortT* Barr[3] = {B0, B1, B2};
  const size_t laneA = (size_t)(m0 + m16) * HID + quad * 8;
  const size_t laneB = (size_t)(n0 + m16) * HID + quad * 8;

  f32x4 acc[4][4] = {};

  for (int k0 = 0; k0 < HID; k0 += 32) {
#pragma unroll
    for (int u = 0; u < LEV * 4; ++u) {
      int t = u * 4 + w;
      int p = t >> 3, q = t & 7;
      const ushortT* g;
      ushortT* s;
      if (p < LEV) {
        g = Aarr[p] + laneA + (size_t)q * 16 * HID + k0;
        s = &As[p][q * 512];
      } else {
        g = Barr[p - LEV] + laneB + (size_t)q * 16 * HID + k0;
        s = &Bs[p - LEV][q * 512];
      }
      gload16(g, s);
    }
    __syncthreads();

    short8 af[LEV][4], bf[LEV][4];
#pragma unroll
    for (int v = 0; v < LEV; ++v)
#pragma unroll
      for (int i = 0; i < 4; ++i) {
        af[v][i] = *(const short8*)&As[v][(wr * 4 + i) * 512 + quad * 128 + m16 * 8];
        bf[v][i] = *(const short8*)&Bs[v][(wc * 4 + i) * 512 + quad * 128 + m16 * 8];
      }
#pragma unroll
    for (int i = 0; i < 4; ++i)
#pragma unroll
      for (int j = 0; j < 4; ++j) {
        acc[i][j] = mfma16(af[0][i], bf[0][j], acc[i][j]);
        acc[i][j] = mfma16(af[0][i], bf[1][j], acc[i][j]);
        acc[i][j] = mfma16(af[1][i], bf[0][j], acc[i][j]);
        if (LEV == 3) {
          acc[i][j] = mfma16(af[1][i], bf[1][j], acc[i][j]);
          acc[i][j] = mfma16(af[0][i], bf[2][j], acc[i][j]);
          acc[i][j] = mfma16(af[2][i], bf[0][j], acc[i][j]);
        }
      }
    __syncthreads();
  }

  const int row0 = m0 + wr * 64;
  const int col0 = n0 + wc * 64;
#pragma unroll
  for (int i = 0; i < 4; ++i)
#pragma unroll
    for (int j = 0; j < 4; ++j) {
#pragma unroll
      for (int r = 0; r < 4; ++r) {
        int row = row0 + i * 16 + quad * 4 + r;
        int col = col0 + j * 16 + m16;
        float v = acc[i][j][r];
        if (MODE == 0) {
          C[(size_t)row * HID + col] = v;
        } else {
          int h = col >> 7, d = col & 127;
          C[(((size_t)h * SEQ + row) << 7) + d] = v;
        }
      }
    }
}

// ================= fp32 fallback GEMM =====================================
template<int MODE>
__global__ __launch_bounds__(256) void gemm_nt(const float* __restrict__ A,
                                               const float* __restrict__ B,
                                               float* __restrict__ C) {
  __shared__ float Asm[16][132];
  __shared__ float Bsm[16][132];
  const int tid = threadIdx.x;
  const int tx = tid & 15, ty = tid >> 4;
  const int m0 = blockIdx.y * 128, n0 = blockIdx.x * 128;
  float acc[8][8] = {};
  for (int k0 = 0; k0 < HID; k0 += 16) {
#pragma unroll
    for (int lp = 0; lp < 2; ++lp) {
      int i = tid + lp * 256;
      int row = i >> 2;
      int col = (i & 3) * 4;
      float4 av = *(const float4*)&A[(size_t)(m0 + row) * HID + k0 + col];
      Asm[col + 0][row] = av.x; Asm[col + 1][row] = av.y;
      Asm[col + 2][row] = av.z; Asm[col + 3][row] = av.w;
      float4 bv = *(const float4*)&B[(size_t)(n0 + row) * HID + k0 + col];
      Bsm[col + 0][row] = bv.x; Bsm[col + 1][row] = bv.y;
      Bsm[col + 2][row] = bv.z; Bsm[col + 3][row] = bv.w;
    }
    __syncthreads();
#pragma unroll
    for (int kk = 0; kk < 16; ++kk) {
      float a[8], b[8];
      *(float4*)&a[0] = *(const float4*)&Asm[kk][ty * 4];
      *(float4*)&a[4] = *(const float4*)&Asm[kk][64 + ty * 4];
      *(float4*)&b[0] = *(const float4*)&Bsm[kk][tx * 4];
      *(float4*)&b[4] = *(const float4*)&Bsm[kk][64 + tx * 4];
#pragma unroll
      for (int i2 = 0; i2 < 8; ++i2)
#pragma unroll
        for (int j2 = 0; j2 < 8; ++j2)
          acc[i2][j2] = fmaf(a[i2], b[j2], acc[i2][j2]);
    }
    __syncthreads();
  }
#pragma unroll
  for (int i2 = 0; i2 < 8; ++i2) {
    int s = m0 + ((i2 < 4) ? (ty * 4 + i2) : (64 + ty * 4 + i2 - 4));
#pragma unroll
    for (int j2 = 0; j2 < 8; ++j2) {
      int o = n0 + ((j2 < 4) ? (tx * 4 + j2) : (64 + tx * 4 + j2 - 4));
      float v = acc[i2][j2];
      if (MODE == 0) {
        C[(size_t)s * HID + o] = v;
      } else {
        int h = o >> 7, d = o & 127;
        C[(((size_t)h * SEQ + s) << 7) + d] = v;
      }
    }
  }
}

// ================= RoPE ====================================================
__global__ void rope_tables_kernel(float* __restrict__ cosT, float* __restrict__ sinT) {
  int t = blockIdx.x;
  int i = threadIdx.x;  // 0..63
  double inv = pow(10000.0, -((double)(2 * i)) / 128.0);
  float ang = (float)t * (float)inv;
  cosT[t * 64 + i] = cosf(ang);
  sinT[t * 64 + i] = sinf(ang);
}

__global__ void rope_apply_kernel(float* __restrict__ Q, float* __restrict__ K,
                                  const int* __restrict__ pos,
                                  const float* __restrict__ cosT,
                                  const float* __restrict__ sinT) {
  int d = threadIdx.x;           // 0..127
  int s = blockIdx.x;
  int h = blockIdx.y;
  float* X = blockIdx.z ? K : Q;
  float* row = X + (((size_t)h * SEQ + s) << 7);
  int p = pos[s];
  int i = d & 63;
  float c = cosT[p * 64 + i];
  float sn = sinT[p * 64 + i];
  float x  = row[d];
  float xo = row[(d < 64) ? (d + 64) : (d - 64)];
  float rot = (d < 64) ? -xo : xo;
  __syncthreads();
  row[d] = x * c + rot * sn;
}

// ================= MFMA flash attention ===================================
// Block: 4 waves, 64 q-rows (wave w owns rows q0+16w..+15). KT=32 k per iter.
// Q,K: 3 bf16 levels (6 products, ~2^-24 score error). V,P: 2 levels (3 products).
// LDS subtile layout (proven in gemm_mfma): element (row, col) of a 16-row
// group at  grp*2048(ushorts per 16x128) ... chunk = 16 rows x 32 cols = 512 us.
__global__ __launch_bounds__(256, 2) void flash_mfma_kernel(
    const ushortT* __restrict__ Qh, const ushortT* __restrict__ Qm, const ushortT* __restrict__ Ql,
    const ushortT* __restrict__ Kh, const ushortT* __restrict__ Km, const ushortT* __restrict__ Kl,
    const ushortT* __restrict__ VtH, const ushortT* __restrict__ VtL,
    float* __restrict__ AO, float* __restrict__ Mb, float* __restrict__ Lb) {
  __shared__ ushortT Ks[3][4096];   // [32 k-rows][128 d] per level, subtiled
  __shared__ ushortT Vts[2][4096];  // [128 d-rows][32 s] per level, subtiled
  __shared__ ushortT Ps[4][2][512]; // per-wave P tile [16 q][32 k], subtiled
  const int tid = threadIdx.x;
  const int w = tid >> 6, l = tid & 63;
  const int m16 = l & 15, quad = l >> 4;
  const int h = blockIdx.y;
  const int qb = 31 - blockIdx.x;     // biggest blocks first
  const int q0 = qb * 64;
  const int qrow = q0 + w * 16;

  const ushortT* Qarr[3] = {Qh, Qm, Ql};
  const ushortT* Karr[3] = {Kh, Km, Kl};
  const ushortT* Varr[2] = {VtH, VtL};

  // Q fragments in registers (wave-private, loaded once)
  short8 qf[3][4];
  {
    size_t qbase = ((size_t)h * SEQ + qrow + m16) * HD + quad * 8;
#pragma unroll
    for (int lv = 0; lv < 3; ++lv)
#pragma unroll
      for (int ks = 0; ks < 4; ++ks)
        qf[lv][ks] = *(const short8*)&Qarr[lv][qbase + ks * 32];
  }

  f32x4 o[8] = {};
  float m_[4] = {-INFINITY, -INFINITY, -INFINITY, -INFINITY};
  float l_[4] = {0.f, 0.f, 0.f, 0.f};

  const int kt_max = 2 * qb + 1;
  for (int kt = 0; kt <= kt_max; ++kt) {
    // ---- stage K (3 lev) + Vt (2 lev): 40 chunks of 1KB, 10 per wave ----
#pragma unroll
    for (int u = 0; u < 10; ++u) {
      int c = u * 4 + w;
      const ushortT* g;
      ushortT* s;
      if (c < 24) {
        int lv = c >> 3, cc = c & 7, st = cc >> 2, cs = cc & 3;
        g = Karr[lv] + ((size_t)h * SEQ + kt * 32 + st * 16 + m16) * HD + cs * 32 + quad * 8;
        s = &Ks[lv][st * 2048 + cs * 512];
      } else {
        int c2 = c - 24, lv = c2 >> 3, dt = c2 & 7;
        g = Varr[lv] + ((size_t)h * HD + dt * 16 + m16) * SEQ + kt * 32 + quad * 8;
        s = &Vts[lv][dt * 512];
      }
      gload16(g, s);
    }
    __syncthreads();

    // ---- QK^T: S[16 q][32 k], 6-product split3 ----
    f32x4 sA[2] = {};
#pragma unroll
    for (int t2 = 0; t2 < 2; ++t2)
#pragma unroll
      for (int ks = 0; ks < 4; ++ks) {
        int off = t2 * 2048 + ks * 512 + quad * 128 + m16 * 8;
        short8 bh = *(const short8*)&Ks[0][off];
        short8 bm = *(const short8*)&Ks[1][off];
        short8 bl = *(const short8*)&Ks[2][off];
        sA[t2] = mfma16(qf[0][ks], bh, sA[t2]);
        sA[t2] = mfma16(qf[0][ks], bm, sA[t2]);
        sA[t2] = mfma16(qf[1][ks], bh, sA[t2]);
        sA[t2] = mfma16(qf[1][ks], bm, sA[t2]);
        sA[t2] = mfma16(qf[0][ks], bl, sA[t2]);
        sA[t2] = mfma16(qf[2][ks], bh, sA[t2]);
      }

    // ---- scale + causal mask ----
    const bool need_mask = (kt >= 2 * qb);
#pragma unroll
    for (int t2 = 0; t2 < 2; ++t2)
#pragma unroll
      for (int r = 0; r < 4; ++r) {
        float v = sA[t2][r] * RSQRT_D;
        if (need_mask) {
          int kg = kt * 32 + t2 * 16 + m16;
          int qg = qrow + quad * 4 + r;
          if (kg > qg) v = -INFINITY;
        }
        sA[t2][r] = v;
      }

    // ---- online softmax (wave-parallel; row lives in 16 lanes of a quad) --
    float tmax[4];
#pragma unroll
    for (int r = 0; r < 4; ++r) tmax[r] = fmaxf(sA[0][r], sA[1][r]);
#pragma unroll
    for (int msk = 1; msk <= 8; msk <<= 1)
#pragma unroll
      for (int r = 0; r < 4; ++r)
        tmax[r] = fmaxf(tmax[r], __shfl_xor(tmax[r], msk));

    float scf[4];
#pragma unroll
    for (int r = 0; r < 4; ++r) {
      float mn = fmaxf(m_[r], tmax[r]);
      scf[r] = expf(m_[r] - mn);
      m_[r] = mn;
    }
    float rs[4];
#pragma unroll
    for (int r = 0; r < 4; ++r) {
      float p0 = expf(sA[0][r] - m_[r]);
      float p1 = expf(sA[1][r] - m_[r]);
      sA[0][r] = p0; sA[1][r] = p1;
      rs[r] = p0 + p1;
    }
#pragma unroll
    for (int msk = 1; msk <= 8; msk <<= 1)
#pragma unroll
      for (int r = 0; r < 4; ++r) rs[r] += __shfl_xor(rs[r], msk);
#pragma unroll
    for (int r = 0; r < 4; ++r) l_[r] = l_[r] * scf[r] + rs[r];

#pragma unroll
    for (int dt = 0; dt < 8; ++dt)
#pragma unroll
      for (int r = 0; r < 4; ++r) o[dt][r] *= scf[r];

    // ---- P -> bf16 split2, relayout via wave-private LDS ----
#pragma unroll
    for (int t2 = 0; t2 < 2; ++t2)
#pragma unroll
      for (int r = 0; r < 4; ++r) {
        float p = sA[t2][r];
        ushortT ph = f2b(p);
        ushortT pl = f2b(p - b2f(ph));
        int off = (t2 * 2 + (m16 >> 3)) * 128 + (quad * 4 + r) * 8 + (m16 & 7);
        Ps[w][0][off] = ph;
        Ps[w][1][off] = pl;
      }

    // ---- PV: O += P * V, 3-product split2 ----
    short8 pah = *(const short8*)&Ps[w][0][quad * 128 + m16 * 8];
    short8 pal = *(const short8*)&Ps[w][1][quad * 128 + m16 * 8];
#pragma unroll
    for (int dt = 0; dt < 8; ++dt) {
      int off = dt * 512 + quad * 128 + m16 * 8;
      short8 vh = *(const short8*)&Vts[0][off];
      short8 vl = *(const short8*)&Vts[1][off];
      o[dt] = mfma16(pah, vh, o[dt]);
      o[dt] = mfma16(pah, vl, o[dt]);
      o[dt] = mfma16(pal, vh, o[dt]);
    }
    __syncthreads();
  }

  // ---- epilogue ----
  float linv[4];
#pragma unroll
  for (int r = 0; r < 4; ++r) linv[r] = 1.f / l_[r];
#pragma unroll
  for (int dt = 0; dt < 8; ++dt)
#pragma unroll
    for (int r = 0; r < 4; ++r)
      AO[(size_t)(qrow + quad * 4 + r) * HID + h * HD + dt * 16 + m16] = o[dt][r] * linv[r];
  if (m16 == 0) {
#pragma unroll
    for (int r = 0; r < 4; ++r) {
      Mb[h * SEQ + qrow + quad * 4 + r] = m_[r];
      Lb[h * SEQ + qrow + quad * 4 + r] = l_[r];
    }
  }
}

// ================= MFMA colsum ============================================
// Block: 64 k-cols (wave w owns 16). K frags in registers (loaded once);
// Q staged 32 rows/step in LDS (3 levels).
__global__ __launch_bounds__(256, 2) void colsum_mfma_kernel(
    const ushortT* __restrict__ Qh, const ushortT* __restrict__ Qm, const ushortT* __restrict__ Ql,
    const ushortT* __restrict__ Kh, const ushortT* __restrict__ Km, const ushortT* __restrict__ Kl,
    const float* __restrict__ Mb, const float* __restrict__ Lb,
    float* __restrict__ HH) {
  __shared__ ushortT Qs[3][4096];   // [32 q-rows][128 d] per level, subtiled
  __shared__ float ms[32], ls[32];
  const int tid = threadIdx.x;
  const int w = tid >> 6, l = tid & 63;
  const int m16 = l & 15, quad = l >> 4;
  const int h = blockIdx.y, kb = blockIdx.x;
  const int k0 = kb * 64;
  const int kg = k0 + w * 16 + m16;   // this lane's k column

  const ushortT* Qarr[3] = {Qh, Qm, Ql};
  const ushortT* Karr[3] = {Kh, Km, Kl};

  // K fragments (wave's 16 k-rows), direct from global, once
  short8 kf[3][4];
  {
    size_t kbase = ((size_t)h * SEQ + k0 + w * 16 + m16) * HD + quad * 8;
#pragma unroll
    for (int lv = 0; lv < 3; ++lv)
#pragma unroll
      for (int ks = 0; ks < 4; ++ks)
        kf[lv][ks] = *(const short8*)&Karr[lv][kbase + ks * 32];
  }

  float acc = 0.f;
  for (int qs = k0; qs < SEQ; qs += 32) {
    // stage Q: 3 lev x 8 chunks = 24, 6 per wave; plus m/l row stats
#pragma unroll
    for (int u = 0; u < 6; ++u) {
      int c = u * 4 + w;
      int lv = c >> 3, cc = c & 7, t2 = cc >> 2, cs = cc & 3;
      const ushortT* g = Qarr[lv] + ((size_t)h * SEQ + qs + t2 * 16 + m16) * HD + cs * 32 + quad * 8;
      gload16(g, &Qs[lv][t2 * 2048 + cs * 512]);
    }
    if (tid < 32) {
      ms[tid] = Mb[h * SEQ + qs + tid];
      ls[tid] = 1.f / Lb[h * SEQ + qs + tid];
    }
    __syncthreads();

#pragma unroll
    for (int t2 = 0; t2 < 2; ++t2) {
      f32x4 sA = {};
#pragma unroll
      for (int ks = 0; ks < 4; ++ks) {
        int off = t2 * 2048 + ks * 512 + quad * 128 + m16 * 8;
        short8 ah = *(const short8*)&Qs[0][off];
        short8 am = *(const short8*)&Qs[1][off];
        short8 al = *(const short8*)&Qs[2][off];
        sA = mfma16(ah, kf[0][ks], sA);
        sA = mfma16(ah, kf[1][ks], sA);
        sA = mfma16(am, kf[0][ks], sA);
        sA = mfma16(am, kf[1][ks], sA);
        sA = mfma16(ah, kf[2][ks], sA);
        sA = mfma16(al, kf[0][ks], sA);
      }
#pragma unroll
      for (int r = 0; r < 4; ++r) {
        int qq = t2 * 16 + quad * 4 + r;   // local q row
        int qglob = qs + qq;
        if (qglob >= kg) {
          float sp = sA[r] * RSQRT_D;
          acc += expf(sp - ms[qq]) * ls[qq];
        }
      }
    }
    __syncthreads();
  }

  acc += __shfl_xor(acc, 16);
  acc += __shfl_xor(acc, 32);
  if (l < 16) HH[h * SEQ + k0 + w * 16 + l] = acc;
}

// ================= fp32 fallback flash attention ==========================
__global__ __launch_bounds__(256) void flash_kernel(const float* __restrict__ Q,
                                                    const float* __restrict__ K,
                                                    const float* __restrict__ V,
                                                    float* __restrict__ AO,
                                                    float* __restrict__ Mb,
                                                    float* __restrict__ Lb) {
  __shared__ float Qs[32][136];
  __shared__ float Ks[32][136];
  __shared__ float Vs[32][136];
  __shared__ float Psm[32][33];
  __shared__ float mrow[32], lrow[32], srow[32];
  const int tid = threadIdx.x;
  const int h = blockIdx.y, qt = blockIdx.x;
  const int q0 = qt * 32;
  const float* Qh = Q + (((size_t)h * SEQ + q0) << 7);
  const float* Kh = K + ((size_t)h * SEQ << 7);
  const float* Vh = V + ((size_t)h * SEQ << 7);
  for (int i = tid; i < 1024; i += 256) {
    int row = i >> 5, c4 = (i & 31) * 4;
    *(float4*)&Qs[row][c4] = *(const float4*)&Qh[i * 4];
  }
  if (tid < 32) { mrow[tid] = -INFINITY; lrow[tid] = 0.f; }
  const int r  = tid >> 3;
  const int sl = tid & 7;
  float o_acc[16] = {};
  for (int kt = 0; kt <= qt; ++kt) {
    __syncthreads();
    for (int i = tid; i < 1024; i += 256) {
      int row = i >> 5, c4 = (i & 31) * 4;
      *(float4*)&Ks[row][c4] = *(const float4*)&Kh[(size_t)kt * 4096 + i * 4];
      *(float4*)&Vs[row][c4] = *(const float4*)&Vh[(size_t)kt * 4096 + i * 4];
    }
    __syncthreads();
    float sacc[4] = {};
#pragma unroll 8
    for (int c = 0; c < 128; c += 4) {
      float4 qv = *(const float4*)&Qs[r][c];
#pragma unroll
      for (int j = 0; j < 4; ++j) {
        float4 kv = *(const float4*)&Ks[sl + 8 * j][c];
        sacc[j] = fmaf(qv.x, kv.x, sacc[j]);
        sacc[j] = fmaf(qv.y, kv.y, sacc[j]);
        sacc[j] = fmaf(qv.z, kv.z, sacc[j]);
        sacc[j] = fmaf(qv.w, kv.w, sacc[j]);
      }
    }
    const int qg = q0 + r;
#pragma unroll
    for (int j = 0; j < 4; ++j) {
      int kg = kt * 32 + sl + 8 * j;
      Psm[r][sl + 8 * j] = (kg <= qg) ? (sacc[j] * RSQRT_D) : -INFINITY;
    }
    __syncthreads();
    if (tid < 32) {
      int rr = tid;
      float mold = mrow[rr];
      float mt = mold;
#pragma unroll
      for (int k2 = 0; k2 < 32; ++k2) mt = fmaxf(mt, Psm[rr][k2]);
      float sc = expf(mold - mt);
      float lsv = 0.f;
#pragma unroll
      for (int k2 = 0; k2 < 32; ++k2) {
        float p = expf(Psm[rr][k2] - mt);
        Psm[rr][k2] = p;
        lsv += p;
      }
      mrow[rr] = mt;
      lrow[rr] = lrow[rr] * sc + lsv;
      srow[rr] = sc;
    }
    __syncthreads();
    float sc = srow[r];
#pragma unroll
    for (int d2 = 0; d2 < 16; ++d2) o_acc[d2] *= sc;
#pragma unroll 4
    for (int k2 = 0; k2 < 32; ++k2) {
      float p = Psm[r][k2];
      float4 v0 = *(const float4*)&Vs[k2][sl * 4];
      float4 v1 = *(const float4*)&Vs[k2][sl * 4 + 32];
      float4 v2 = *(const float4*)&Vs[k2][sl * 4 + 64];
      float4 v3 = *(const float4*)&Vs[k2][sl * 4 + 96];
      o_acc[0]  = fmaf(p, v0.x, o_acc[0]);  o_acc[1]  = fmaf(p, v0.y, o_acc[1]);
      o_acc[2]  = fmaf(p, v0.z, o_acc[2]);  o_acc[3]  = fmaf(p, v0.w, o_acc[3]);
      o_acc[4]  = fmaf(p, v1.x, o_acc[4]);  o_acc[5]  = fmaf(p, v1.y, o_acc[5]);
      o_acc[6]  = fmaf(p, v1.z, o_acc[6]);  o_acc[7]  = fmaf(p, v1.w, o_acc[7]);
      o_acc[8]  = fmaf(p, v2.x, o_acc[8]);  o_acc[9]  = fmaf(p, v2.y, o_acc[9]);
      o_acc[10] = fmaf(p, v2.z, o_acc[10]); o_acc[11] = fmaf(p, v2.w, o_acc[11]);
      o_acc[12] = fmaf(p, v3.x, o_acc[12]); o_acc[13] = fmaf(p, v3.y, o_acc[13]);
      o_acc[14] = fmaf(p, v3.z, o_acc[14]); o_acc[15] = fmaf(p, v3.w, o_acc[15]);
    }
  }
  float linv = 1.f / lrow[r];
  int s = q0 + r;
  float* orow = &AO[(size_t)s * HID + h * 128];
#pragma unroll
  for (int m = 0; m < 4; ++m) {
    float4 wv;
    wv.x = o_acc[4 * m + 0] * linv; wv.y = o_acc[4 * m + 1] * linv;
    wv.z = o_acc[4 * m + 2] * linv; wv.w = o_acc[4 * m + 3] * linv;
    *(float4*)&orow[sl * 4 + 32 * m] = wv;
  }
  if (tid < 32) {
    Mb[h * SEQ + q0 + tid] = mrow[tid];
    Lb[h * SEQ + q0 + tid] = lrow[tid];
  }
}

// ================= fp32 fallback colsum ===================================
__global__ __launch_bounds__(256) void colsum_kernel(const float* __restrict__ Q,
                                                     const float* __restrict__ K,
                                                     const float* __restrict__ Mb,
                                                     const float* __restrict__ Lb,
                                                     float* __restrict__ HH) {
  __shared__ float Ks[32][136];
  __shared__ float Qs[32][136];
  __shared__ float ms[32], ls[32];
  __shared__ float part[32][9];
  const int tid = threadIdx.x;
  const int h = blockIdx.y, kt = blockIdx.x;
  const int k0 = kt * 32;
  const float* Kh = K + ((size_t)h * SEQ << 7);
  const float* Qh = Q + ((size_t)h * SEQ << 7);
  for (int i = tid; i < 1024; i += 256) {
    int row = i >> 5, c4 = (i & 31) * 4;
    *(float4*)&Ks[row][c4] = *(const float4*)&Kh[(size_t)k0 * 128 + i * 4];
  }
  const int c = tid >> 3;
  const int qsl = tid & 7;
  const int kg = k0 + c;
  float acc = 0.f;
  for (int qt = kt; qt < NKT; ++qt) {
    __syncthreads();
    for (int i = tid; i < 1024; i += 256) {
      int row = i >> 5, c4 = (i & 31) * 4;
      *(float4*)&Qs[row][c4] = *(const float4*)&Qh[(size_t)qt * 4096 + i * 4];
    }
    if (tid < 32) {
      ms[tid] = Mb[h * SEQ + qt * 32 + tid];
      ls[tid] = 1.f / Lb[h * SEQ + qt * 32 + tid];
    }
    __syncthreads();
    float dacc[4] = {};
#pragma unroll 8
    for (int cc = 0; cc < 128; cc += 4) {
      float4 kv = *(const float4*)&Ks[c][cc];
#pragma unroll
      for (int j = 0; j < 4; ++j) {
        float4 qv = *(const float4*)&Qs[qsl + 8 * j][cc];
        dacc[j] = fmaf(qv.x, kv.x, dacc[j]);
        dacc[j] = fmaf(qv.y, kv.y, dacc[j]);
        dacc[j] = fmaf(qv.z, kv.z, dacc[j]);
        dacc[j] = fmaf(qv.w, kv.w, dacc[j]);
      }
    }
#pragma unroll
    for (int j = 0; j < 4; ++j) {
      int qr = qsl + 8 * j;
      int qg = qt * 32 + qr;
      if (qg >= kg)
        acc += expf(dacc[j] * RSQRT_D - ms[qr]) * ls[qr];
    }
  }
  part[c][qsl] = acc;
  __syncthreads();
  if (qsl == 0) {
    float ssum = 0.f;
#pragma unroll
    for (int t2 = 0; t2 < 8; ++t2) ssum += part[c][t2];
    HH[h * SEQ + k0 + c] = ssum;
  }
}

// ================= top-k ===================================================
__global__ __launch_bounds__(256) void topk_kernel(const float* __restrict__ HH,
                                                   int* __restrict__ keep) {
  __shared__ float vals[SELN];
  __shared__ float rv[256];
  __shared__ int   ri[256];
  __shared__ int   sel[HHSZ];
  const int h = blockIdx.x, tid = threadIdx.x;
  for (int i = tid; i < SELN; i += 256) vals[i] = HH[h * SEQ + i];
  __syncthreads();
  for (int it = 0; it < HHSZ; ++it) {
    float bv = -INFINITY; int bi = 0x7fffffff;
    for (int i = tid; i < SELN; i += 256) {
      float v = vals[i];
      if (v > bv || (v == bv && i < bi)) { bv = v; bi = i; }
    }
    rv[tid] = bv; ri[tid] = bi;
    __syncthreads();
    for (int sft = 128; sft > 0; sft >>= 1) {
      if (tid < sft) {
        if (rv[tid + sft] > rv[tid] ||
            (rv[tid + sft] == rv[tid] && ri[tid + sft] < ri[tid])) {
          rv[tid] = rv[tid + sft]; ri[tid] = ri[tid + sft];
        }
      }
      __syncthreads();
    }
    if (tid == 0) { sel[it] = ri[0]; vals[ri[0]] = -INFINITY; }
    __syncthreads();
  }
  for (int ph = 0; ph < HHSZ; ++ph) {
    int i = (ph & 1) + 2 * tid;
    if (i + 1 < HHSZ) {
      int a = sel[i], b = sel[i + 1];
      if (a > b) { sel[i] = b; sel[i + 1] = a; }
    }
    __syncthreads();
  }
  for (int i = tid; i < HHSZ; i += 256) keep[h * CACHE + i] = sel[i];
  for (int i = tid; i < RECENT; i += 256) keep[h * CACHE + HHSZ + i] = SELN + i;
}

// ================= gather ==================================================
__global__ void gather_kernel(const float* __restrict__ K, const float* __restrict__ V,
                              const float* __restrict__ HH, const int* __restrict__ keep,
                              float* __restrict__ k_out, float* __restrict__ v_out,
                              float* __restrict__ hh_out) {
  const int j = blockIdx.x;
  const int h = blockIdx.y;
  const int d = threadIdx.x;
  const int idx = keep[h * CACHE + j];
  size_t src = (((size_t)h * SEQ + idx) << 7) + d;
  size_t dst = (((size_t)h * CACHE + j) << 7) + d;
  k_out[dst] = K[src];
  v_out[dst] = V[src];
  if (d == 0) hh_out[h * CACHE + j] = HH[h * SEQ + idx];
}

// ================= launch ==================================================
extern "C" void kernel_launch(void* const* d_in, const int* in_sizes, int n_in,
                              void* d_out, int out_size, void* d_ws, size_t ws_size,
                              hipStream_t stream) {
  (void)in_sizes; (void)n_in; (void)out_size;
  const float* hs  = (const float*)d_in[0];
  const int*   pos = (const int*)d_in[1];
  const float* Wq  = (const float*)d_in[2];
  const float* Wk  = (const float*)d_in[3];
  const float* Wv  = (const float*)d_in[4];
  const float* Wo  = (const float*)d_in[5];

  float* out = (float*)d_out;                 // [2048][4096]
  float* khh = out + (size_t)SEQ * HID;       // [32][768][128]
  float* vhh = khh + (size_t)NH * CACHE * HD;
  float* hhk = vhh + (size_t)NH * CACHE * HD; // [32][768]

  char* p = (char*)d_ws;
  auto alloc = [&](size_t bytes) { char* r = p; p += (bytes + 255) & ~(size_t)255; return r; };

  float* Qw   = (float*)alloc((size_t)NH * SEQ * HD * 4);
  float* Kw   = (float*)alloc((size_t)NH * SEQ * HD * 4);
  float* Vw   = (float*)alloc((size_t)NH * SEQ * HD * 4);
  float* AO   = (float*)alloc((size_t)SEQ * HID * 4);
  float* Mb   = (float*)alloc((size_t)NH * SEQ * 4);
  float* Lb   = (float*)alloc((size_t)NH * SEQ * 4);
  float* HH   = (float*)alloc((size_t)NH * SEQ * 4);
  float* cosT = (float*)alloc((size_t)SEQ * 64 * 4);
  float* sinT = (float*)alloc((size_t)SEQ * 64 * 4);
  int*   keep = (int*)alloc((size_t)NH * CACHE * 4);
  // bf16 split buffers
  ushortT* hsH = (ushortT*)alloc((size_t)SEQ * HID * 2);
  ushortT* hsM = (ushortT*)alloc((size_t)SEQ * HID * 2);
  ushortT* hsL = (ushortT*)alloc((size_t)SEQ * HID * 2);
  ushortT* WH  = (ushortT*)alloc((size_t)HID * HID * 2);
  ushortT* WM  = (ushortT*)alloc((size_t)HID * HID * 2);
  ushortT* WL  = (ushortT*)alloc((size_t)HID * HID * 2);
  const size_t needed = (size_t)(p - (char*)d_ws);
  const bool use_mfma = ws_size >= needed;

  const dim3 ggrid(32, 16);
  const int n4hs = SEQ * HID / 4;    // 2097152
  const int n4w  = HID * HID / 4;    // 4194304

  if (use_mfma) {
    split3_kernel<<<n4hs / 256, 256, 0, stream>>>(hs, hsH, hsM, hsL, n4hs);
    split3_kernel<<<n4w / 256, 256, 0, stream>>>(Wq, WH, WM, WL, n4w);
    gemm_mfma<3, 1><<<ggrid, 256, 0, stream>>>(hsH, hsM, hsL, WH, WM, WL, Qw);
    split3_kernel<<<n4w / 256, 256, 0, stream>>>(Wk, WH, WM, WL, n4w);
    gemm_mfma<3, 1><<<ggrid, 256, 0, stream>>>(hsH, hsM, hsL, WH, WM, WL, Kw);
    split2_kernel<<<n4w / 256, 256, 0, stream>>>(Wv, WH, WM, n4w);
    gemm_mfma<2, 1><<<ggrid, 256, 0, stream>>>(hsH, hsM, nullptr, WH, WM, nullptr, Vw);
  } else {
    gemm_nt<1><<<ggrid, 256, 0, stream>>>(hs, Wq, Qw);
    gemm_nt<1><<<ggrid, 256, 0, stream>>>(hs, Wk, Kw);
    gemm_nt<1><<<ggrid, 256, 0, stream>>>(hs, Wv, Vw);
  }

  rope_tables_kernel<<<SEQ, 64, 0, stream>>>(cosT, sinT);
  rope_apply_kernel<<<dim3(SEQ, NH, 2), 128, 0, stream>>>(Qw, Kw, pos, cosT, sinT);

  if (use_mfma) {
    // Re-use W-split buffers for Q/K 3-level splits; hs-split buffers for Vt.
    const size_t QKOFF = (size_t)NH * SEQ * HD;   // 8.4M ushorts
    const int n4qk = NH * SEQ * HD / 4;
    split3_kernel<<<n4qk / 256, 256, 0, stream>>>(Qw, WH, WM, WL, n4qk);
    split3_kernel<<<n4qk / 256, 256, 0, stream>>>(Kw, WH + QKOFF, WM + QKOFF, WL + QKOFF, n4qk);
    split2t_kernel<<<dim3(64, 4, 32), 256, 0, stream>>>(Vw, hsH, hsM);
    flash_mfma_kernel<<<dim3(32, 32), 256, 0, stream>>>(
        WH, WM, WL, WH + QKOFF, WM + QKOFF, WL + QKOFF, hsH, hsM, AO, Mb, Lb);
    colsum_mfma_kernel<<<dim3(32, 32), 256, 0, stream>>>(
        WH, WM, WL, WH + QKOFF, WM + QKOFF, WL + QKOFF, Mb, Lb, HH);
  } else {
    flash_kernel<<<dim3(NKT, NH), 256, 0, stream>>>(Qw, Kw, Vw, AO, Mb, Lb);
    colsum_kernel<<<dim3(NKT, NH), 256, 0, stream>>>(Qw, Kw, Mb, Lb, HH);
  }

  if (use_mfma) {
    split2_kernel<<<n4w / 256, 256, 0, stream>>>(Wo, WH, WM, n4w);
    split2_kernel<<<n4hs / 256, 256, 0, stream>>>(AO, hsH, hsM, n4hs);  // reuse hs buffers
    gemm_mfma<2, 0><<<ggrid, 256, 0, stream>>>(hsH, hsM, nullptr, WH, WM, nullptr, out);
  } else {
    gemm_nt<0><<<ggrid, 256, 0, stream>>>(AO, Wo, out);
  }

  topk_kernel<<<NH, 256, 0, stream>>>(HH, keep);
  gather_kernel<<<dim3(CACHE, NH), 128, 0, stream>>>(Kw, Vw, HH, keep, khh, vhh, hhk);
}

// Round 2
// 2672.085 us; speedup vs baseline: 1.7817x; 1.0284x over previous
//
#include <hip/hip_runtime.h>
#include <hip/hip_bf16.h>
#include <math.h>

#define HID 4096
#define NH 32
#define HD 128
#define SEQ 2048
#define NKT 64
#define HHSZ 256
#define RECENT 512
#define CACHE 768
#define SELN 1536
#define RSQRT_D 0.08838834764831845f
// RSQRT_D * log2(e): scores scaled into log2 domain for exp2-based softmax
#define SCALE2 0.12751749522423355f

typedef unsigned short ushortT;
typedef __attribute__((ext_vector_type(8))) short short8;
typedef __attribute__((ext_vector_type(4))) float f32x4;

// ================= bf16 split helpers =====================================
__device__ __forceinline__ ushortT f2b(float f) {
  union { __hip_bfloat16 h; ushortT u; } v;
  v.h = __float2bfloat16(f);
  return v.u;
}
__device__ __forceinline__ float b2f(ushortT u) {
  union { unsigned int i; float f; } v;
  v.i = ((unsigned int)u) << 16;
  return v.f;
}
__device__ __forceinline__ void split3(float x, ushortT& h, ushortT& m, ushortT& l) {
  h = f2b(x);
  float r = x - b2f(h);
  m = f2b(r);
  float r2 = r - b2f(m);
  l = f2b(r2);
}
__device__ __forceinline__ void split2(float x, ushortT& h, ushortT& l) {
  h = f2b(x);
  l = f2b(x - b2f(h));
}

__global__ __launch_bounds__(256) void split3_kernel(const float* __restrict__ X,
    ushortT* __restrict__ o0, ushortT* __restrict__ o1, ushortT* __restrict__ o2, int n4) {
  int i = blockIdx.x * 256 + threadIdx.x;
  if (i >= n4) return;
  float4 x = ((const float4*)X)[i];
  ushort4 a, b, c;
  split3(x.x, a.x, b.x, c.x);
  split3(x.y, a.y, b.y, c.y);
  split3(x.z, a.z, b.z, c.z);
  split3(x.w, a.w, b.w, c.w);
  ((ushort4*)o0)[i] = a;
  ((ushort4*)o1)[i] = b;
  ((ushort4*)o2)[i] = c;
}
__global__ __launch_bounds__(256) void split2_kernel(const float* __restrict__ X,
    ushortT* __restrict__ o0, ushortT* __restrict__ o1, int n4) {
  int i = blockIdx.x * 256 + threadIdx.x;
  if (i >= n4) return;
  float4 x = ((const float4*)X)[i];
  ushort4 a, b;
  split2(x.x, a.x, b.x);
  split2(x.y, a.y, b.y);
  split2(x.z, a.z, b.z);
  split2(x.w, a.w, b.w);
  ((ushort4*)o0)[i] = a;
  ((ushort4*)o1)[i] = b;
}

// split3 with fused RoPE: X is [h][s][128] fp32 (un-roped); outputs roped splits.
__global__ __launch_bounds__(256) void split3_rope_kernel(const float* __restrict__ X,
    const int* __restrict__ pos, const float* __restrict__ cosT, const float* __restrict__ sinT,
    ushortT* __restrict__ o0, ushortT* __restrict__ o1, ushortT* __restrict__ o2, int n4) {
  int i = blockIdx.x * 256 + threadIdx.x;
  if (i >= n4) return;
  float4 x = ((const float4*)X)[i];
  float4 y = ((const float4*)X)[i ^ 16];   // partner half (d ^ 64)
  int d4 = i & 31;                          // float4 index in 128-elem row
  int row = i >> 5;                         // h*SEQ + s
  int s = row & (SEQ - 1);
  int p = pos[s];
  int d = d4 * 4;
  float4 c = *(const float4*)&cosT[p * 64 + (d & 63)];
  float4 sn = *(const float4*)&sinT[p * 64 + (d & 63)];
  float sg = (d < 64) ? -1.f : 1.f;
  float4 v;
  v.x = x.x * c.x + sg * y.x * sn.x;
  v.y = x.y * c.y + sg * y.y * sn.y;
  v.z = x.z * c.z + sg * y.z * sn.z;
  v.w = x.w * c.w + sg * y.w * sn.w;
  ushort4 a, b, cc;
  split3(v.x, a.x, b.x, cc.x);
  split3(v.y, a.y, b.y, cc.y);
  split3(v.z, a.z, b.z, cc.z);
  split3(v.w, a.w, b.w, cc.w);
  ((ushort4*)o0)[i] = a;
  ((ushort4*)o1)[i] = b;
  ((ushort4*)o2)[i] = cc;
}

// split V [h][s][128] fp32 -> transposed bf16 levels [h][128][2048]
__global__ __launch_bounds__(256) void split2t_kernel(const float* __restrict__ V,
    ushortT* __restrict__ oH, ushortT* __restrict__ oL) {
  __shared__ float T[32][33];
  const int h = blockIdx.z, s0 = blockIdx.x * 32, d0 = blockIdx.y * 32;
  const int t = threadIdx.x;
  {
    int sr = t >> 3, dc = (t & 7) * 4;
    float4 v = *(const float4*)&V[(((size_t)h * SEQ + s0 + sr) << 7) + d0 + dc];
    T[sr][dc + 0] = v.x; T[sr][dc + 1] = v.y;
    T[sr][dc + 2] = v.z; T[sr][dc + 3] = v.w;
  }
  __syncthreads();
  int dr = t >> 3, sc = (t & 7) * 4;
  ushort4 a, b;
  split2(T[sc + 0][dr], a.x, b.x);
  split2(T[sc + 1][dr], a.y, b.y);
  split2(T[sc + 2][dr], a.z, b.z);
  split2(T[sc + 3][dr], a.w, b.w);
  size_t dst = ((size_t)h * HD + d0 + dr) * SEQ + s0 + sc;
  *(ushort4*)&oH[dst] = a;
  *(ushort4*)&oL[dst] = b;
}

// ================= async global->LDS ======================================
__device__ __forceinline__ void gload16(const void* g, void* lds) {
  __builtin_amdgcn_global_load_lds(
      (const __attribute__((address_space(1))) unsigned int*)g,
      (__attribute__((address_space(3))) unsigned int*)lds, 16, 0, 0);
}

__device__ __forceinline__ f32x4 mfma16(short8 a, short8 b, f32x4 c) {
  return __builtin_amdgcn_mfma_f32_16x16x32_bf16(a, b, c, 0, 0, 0);
}

// ================= split-bf16 MFMA GEMM  C = A * B^T ======================
template<int LEV, int MODE>
__global__ __launch_bounds__(256, 2) void gemm_mfma(
    const ushortT* __restrict__ A0, const ushortT* __restrict__ A1, const ushortT* __restrict__ A2,
    const ushortT* __restrict__ B0, const ushortT* __restrict__ B1, const ushortT* __restrict__ B2,
    float* __restrict__ C) {
  __shared__ ushortT As[LEV][4096];
  __shared__ ushortT Bs[LEV][4096];
  const int tid = threadIdx.x;
  const int w = tid >> 6, l = tid & 63;
  const int m16 = l & 15, quad = l >> 4;
  const int wr = w >> 1, wc = w & 1;
  // XCD-chunked bijective swizzle: 64 consecutive blocks per XCD share A-panels
  const int id = blockIdx.y * 32 + blockIdx.x;          // 0..511
  const int nid = (id & 7) * 64 + (id >> 3);
  const int m0 = (nid >> 5) * 128, n0 = (nid & 31) * 128;
  const ushortT* Aarr[3] = {A0, A1, A2};
  const ushortT* Barr[3] = {B0, B1, B2};
  const size_t laneA = (size_t)(m0 + m16) * HID + quad * 8;
  const size_t laneB = (size_t)(n0 + m16) * HID + quad * 8;

  f32x4 acc[4][4] = {};

  for (int k0 = 0; k0 < HID; k0 += 32) {
#pragma unroll
    for (int u = 0; u < LEV * 4; ++u) {
      int t = u * 4 + w;
      int p = t >> 3, q = t & 7;
      const ushortT* g;
      ushortT* s;
      if (p < LEV) {
        g = Aarr[p] + laneA + (size_t)q * 16 * HID + k0;
        s = &As[p][q * 512];
      } else {
        g = Barr[p - LEV] + laneB + (size_t)q * 16 * HID + k0;
        s = &Bs[p - LEV][q * 512];
      }
      gload16(g, s);
    }
    __syncthreads();

    short8 af[LEV][4], bf[LEV][4];
#pragma unroll
    for (int v = 0; v < LEV; ++v)
#pragma unroll
      for (int i = 0; i < 4; ++i) {
        af[v][i] = *(const short8*)&As[v][(wr * 4 + i) * 512 + quad * 128 + m16 * 8];
        bf[v][i] = *(const short8*)&Bs[v][(wc * 4 + i) * 512 + quad * 128 + m16 * 8];
      }
#pragma unroll
    for (int i = 0; i < 4; ++i)
#pragma unroll
      for (int j = 0; j < 4; ++j) {
        acc[i][j] = mfma16(af[0][i], bf[0][j], acc[i][j]);
        acc[i][j] = mfma16(af[0][i], bf[1][j], acc[i][j]);
        acc[i][j] = mfma16(af[1][i], bf[0][j], acc[i][j]);
        if (LEV == 3) {
          acc[i][j] = mfma16(af[1][i], bf[1][j], acc[i][j]);
          acc[i][j] = mfma16(af[0][i], bf[2][j], acc[i][j]);
          acc[i][j] = mfma16(af[2][i], bf[0][j], acc[i][j]);
        }
      }
    __syncthreads();
  }

  const int row0 = m0 + wr * 64;
  const int col0 = n0 + wc * 64;
#pragma unroll
  for (int i = 0; i < 4; ++i)
#pragma unroll
    for (int j = 0; j < 4; ++j) {
#pragma unroll
      for (int r = 0; r < 4; ++r) {
        int row = row0 + i * 16 + quad * 4 + r;
        int col = col0 + j * 16 + m16;
        float v = acc[i][j][r];
        if (MODE == 0) {
          C[(size_t)row * HID + col] = v;
        } else {
          int h = col >> 7, d = col & 127;
          C[(((size_t)h * SEQ + row) << 7) + d] = v;
        }
      }
    }
}

// ================= fp32 fallback GEMM =====================================
template<int MODE>
__global__ __launch_bounds__(256) void gemm_nt(const float* __restrict__ A,
                                               const float* __restrict__ B,
                                               float* __restrict__ C) {
  __shared__ float Asm[16][132];
  __shared__ float Bsm[16][132];
  const int tid = threadIdx.x;
  const int tx = tid & 15, ty = tid >> 4;
  const int m0 = blockIdx.y * 128, n0 = blockIdx.x * 128;
  float acc[8][8] = {};
  for (int k0 = 0; k0 < HID; k0 += 16) {
#pragma unroll
    for (int lp = 0; lp < 2; ++lp) {
      int i = tid + lp * 256;
      int row = i >> 2;
      int col = (i & 3) * 4;
      float4 av = *(const float4*)&A[(size_t)(m0 + row) * HID + k0 + col];
      Asm[col + 0][row] = av.x; Asm[col + 1][row] = av.y;
      Asm[col + 2][row] = av.z; Asm[col + 3][row] = av.w;
      float4 bv = *(const float4*)&B[(size_t)(n0 + row) * HID + k0 + col];
      Bsm[col + 0][row] = bv.x; Bsm[col + 1][row] = bv.y;
      Bsm[col + 2][row] = bv.z; Bsm[col + 3][row] = bv.w;
    }
    __syncthreads();
#pragma unroll
    for (int kk = 0; kk < 16; ++kk) {
      float a[8], b[8];
      *(float4*)&a[0] = *(const float4*)&Asm[kk][ty * 4];
      *(float4*)&a[4] = *(const float4*)&Asm[kk][64 + ty * 4];
      *(float4*)&b[0] = *(const float4*)&Bsm[kk][tx * 4];
      *(float4*)&b[4] = *(const float4*)&Bsm[kk][64 + tx * 4];
#pragma unroll
      for (int i2 = 0; i2 < 8; ++i2)
#pragma unroll
        for (int j2 = 0; j2 < 8; ++j2)
          acc[i2][j2] = fmaf(a[i2], b[j2], acc[i2][j2]);
    }
    __syncthreads();
  }
#pragma unroll
  for (int i2 = 0; i2 < 8; ++i2) {
    int s = m0 + ((i2 < 4) ? (ty * 4 + i2) : (64 + ty * 4 + i2 - 4));
#pragma unroll
    for (int j2 = 0; j2 < 8; ++j2) {
      int o = n0 + ((j2 < 4) ? (tx * 4 + j2) : (64 + tx * 4 + j2 - 4));
      float v = acc[i2][j2];
      if (MODE == 0) {
        C[(size_t)s * HID + o] = v;
      } else {
        int h = o >> 7, d = o & 127;
        C[(((size_t)h * SEQ + s) << 7) + d] = v;
      }
    }
  }
}

// ================= RoPE ====================================================
__global__ void rope_tables_kernel(float* __restrict__ cosT, float* __restrict__ sinT) {
  int t = blockIdx.x;
  int i = threadIdx.x;  // 0..63
  double inv = pow(10000.0, -((double)(2 * i)) / 128.0);
  float ang = (float)t * (float)inv;
  cosT[t * 64 + i] = cosf(ang);
  sinT[t * 64 + i] = sinf(ang);
}

// fallback-path rope (in-place on fp32 Q/K)
__global__ void rope_apply_kernel(float* __restrict__ Q, float* __restrict__ K,
                                  const int* __restrict__ pos,
                                  const float* __restrict__ cosT,
                                  const float* __restrict__ sinT) {
  int d = threadIdx.x;           // 0..127
  int s = blockIdx.x;
  int h = blockIdx.y;
  float* X = blockIdx.z ? K : Q;
  float* row = X + (((size_t)h * SEQ + s) << 7);
  int p = pos[s];
  int i = d & 63;
  float c = cosT[p * 64 + i];
  float sn = sinT[p * 64 + i];
  float x  = row[d];
  float xo = row[(d < 64) ? (d + 64) : (d - 64)];
  float rot = (d < 64) ? -xo : xo;
  __syncthreads();
  row[d] = x * c + rot * sn;
}

// ================= MFMA flash attention ===================================
// Block: 4 waves, 64 q-rows. Softmax in log2 domain (exp2), defer-rescale.
// Grid 1024 flat: swizzled so all heads' biggest q-blocks launch first and
// each XCD co-hosts a 4-head group (K/V L2-resident).
__global__ __launch_bounds__(256, 3) void flash_mfma_kernel(
    const ushortT* __restrict__ Qh, const ushortT* __restrict__ Qm, const ushortT* __restrict__ Ql,
    const ushortT* __restrict__ Kh, const ushortT* __restrict__ Km, const ushortT* __restrict__ Kl,
    const ushortT* __restrict__ VtH, const ushortT* __restrict__ VtL,
    ushortT* __restrict__ AOH, ushortT* __restrict__ AOM,
    float* __restrict__ Mb, float* __restrict__ Lb) {
  __shared__ ushortT Ks[3][4096];   // [32 k-rows][128 d] per level, subtiled
  __shared__ ushortT Vts[2][4096];  // [128 d-rows][32 s] per level, subtiled
  __shared__ ushortT Ps[4][2][512]; // per-wave P tile [16 q][32 k], subtiled
  const int tid = threadIdx.x;
  const int w = tid >> 6, l = tid & 63;
  const int m16 = l & 15, quad = l >> 4;
  const int f = blockIdx.x;
  const int xcd = f & 7, g = f >> 3;
  const int h = xcd * 4 + (g >> 5);   // 4 heads per XCD group
  const int qb = 31 - (g & 31);       // biggest blocks first everywhere
  const int q0 = qb * 64;
  const int qrow = q0 + w * 16;

  const ushortT* Qarr[3] = {Qh, Qm, Ql};
  const ushortT* Karr[3] = {Kh, Km, Kl};
  const ushortT* Varr[2] = {VtH, VtL};

  // Q fragments in registers (wave-private, loaded once)
  short8 qf[3][4];
  {
    size_t qbase = ((size_t)h * SEQ + qrow + m16) * HD + quad * 8;
#pragma unroll
    for (int lv = 0; lv < 3; ++lv)
#pragma unroll
      for (int ks = 0; ks < 4; ++ks)
        qf[lv][ks] = *(const short8*)&Qarr[lv][qbase + ks * 32];
  }

  f32x4 o[8] = {};
  float m_[4] = {-INFINITY, -INFINITY, -INFINITY, -INFINITY};
  float l_[4] = {0.f, 0.f, 0.f, 0.f};

  const int kt_max = 2 * qb + 1;
  const int my_ktmax = 2 * qb + ((w >= 2) ? 1 : 0);   // waves 0,1 skip last tile
  for (int kt = 0; kt <= kt_max; ++kt) {
    // ---- stage K (3 lev) + Vt (2 lev): 40 chunks of 1KB, 10 per wave ----
#pragma unroll
    for (int u = 0; u < 10; ++u) {
      int c = u * 4 + w;
      const ushortT* g2;
      ushortT* s;
      if (c < 24) {
        int lv = c >> 3, cc = c & 7, st = cc >> 2, cs = cc & 3;
        g2 = Karr[lv] + ((size_t)h * SEQ + kt * 32 + st * 16 + m16) * HD + cs * 32 + quad * 8;
        s = &Ks[lv][st * 2048 + cs * 512];
      } else {
        int c2 = c - 24, lv = c2 >> 3, dt = c2 & 7;
        g2 = Varr[lv] + ((size_t)h * HD + dt * 16 + m16) * SEQ + kt * 32 + quad * 8;
        s = &Vts[lv][dt * 512];
      }
      gload16(g2, s);
    }
    __syncthreads();

    if (kt <= my_ktmax) {
      // ---- QK^T: S[16 q][32 k], 6-product split3 ----
      f32x4 sA[2] = {};
#pragma unroll
      for (int t2 = 0; t2 < 2; ++t2)
#pragma unroll
        for (int ks = 0; ks < 4; ++ks) {
          int off = t2 * 2048 + ks * 512 + quad * 128 + m16 * 8;
          short8 bh = *(const short8*)&Ks[0][off];
          short8 bm = *(const short8*)&Ks[1][off];
          short8 bl = *(const short8*)&Ks[2][off];
          sA[t2] = mfma16(qf[0][ks], bh, sA[t2]);
          sA[t2] = mfma16(qf[0][ks], bm, sA[t2]);
          sA[t2] = mfma16(qf[1][ks], bh, sA[t2]);
          sA[t2] = mfma16(qf[1][ks], bm, sA[t2]);
          sA[t2] = mfma16(qf[0][ks], bl, sA[t2]);
          sA[t2] = mfma16(qf[2][ks], bh, sA[t2]);
        }

      // ---- scale (log2 domain) + causal mask (per-wave tight) ----
      const bool need_mask = (kt * 32 + 31 > qrow);
#pragma unroll
      for (int t2 = 0; t2 < 2; ++t2)
#pragma unroll
        for (int r = 0; r < 4; ++r) {
          float v = sA[t2][r] * SCALE2;
          if (need_mask) {
            int kg = kt * 32 + t2 * 16 + m16;
            int qg = qrow + quad * 4 + r;
            if (kg > qg) v = -INFINITY;
          }
          sA[t2][r] = v;
        }

      // ---- online softmax, wave-parallel, defer-rescale ----
      float tmax[4];
#pragma unroll
      for (int r = 0; r < 4; ++r) tmax[r] = fmaxf(sA[0][r], sA[1][r]);
#pragma unroll
      for (int msk = 1; msk <= 8; msk <<= 1)
#pragma unroll
        for (int r = 0; r < 4; ++r)
          tmax[r] = fmaxf(tmax[r], __shfl_xor(tmax[r], msk));

      bool small = true;
#pragma unroll
      for (int r = 0; r < 4; ++r) small = small && (tmax[r] <= m_[r] + 11.0f);
      if (!__all(small)) {
#pragma unroll
        for (int r = 0; r < 4; ++r) {
          float mn = fmaxf(m_[r], tmax[r]);
          float sc = exp2f(m_[r] - mn);
          m_[r] = mn;
          l_[r] *= sc;
#pragma unroll
          for (int dt = 0; dt < 8; ++dt) o[dt][r] *= sc;
        }
      }
      float rs[4];
#pragma unroll
      for (int r = 0; r < 4; ++r) {
        float p0 = exp2f(sA[0][r] - m_[r]);
        float p1 = exp2f(sA[1][r] - m_[r]);
        sA[0][r] = p0; sA[1][r] = p1;
        rs[r] = p0 + p1;
      }
#pragma unroll
      for (int msk = 1; msk <= 8; msk <<= 1)
#pragma unroll
        for (int r = 0; r < 4; ++r) rs[r] += __shfl_xor(rs[r], msk);
#pragma unroll
      for (int r = 0; r < 4; ++r) l_[r] += rs[r];

      // ---- P -> bf16 split2, relayout via wave-private LDS ----
#pragma unroll
      for (int t2 = 0; t2 < 2; ++t2)
#pragma unroll
        for (int r = 0; r < 4; ++r) {
          float p = sA[t2][r];
          ushortT ph = f2b(p);
          ushortT pl = f2b(p - b2f(ph));
          int off = (t2 * 2 + (m16 >> 3)) * 128 + (quad * 4 + r) * 8 + (m16 & 7);
          Ps[w][0][off] = ph;
          Ps[w][1][off] = pl;
        }

      // ---- PV: O += P * V, 3-product split2 ----
      short8 pah = *(const short8*)&Ps[w][0][quad * 128 + m16 * 8];
      short8 pal = *(const short8*)&Ps[w][1][quad * 128 + m16 * 8];
#pragma unroll
      for (int dt = 0; dt < 8; ++dt) {
        int off = dt * 512 + quad * 128 + m16 * 8;
        short8 vh = *(const short8*)&Vts[0][off];
        short8 vl = *(const short8*)&Vts[1][off];
        o[dt] = mfma16(pah, vh, o[dt]);
        o[dt] = mfma16(pah, vl, o[dt]);
        o[dt] = mfma16(pal, vh, o[dt]);
      }
    }
    __syncthreads();
  }

  // ---- epilogue: write AO directly as split2 bf16 ----
  float linv[4];
#pragma unroll
  for (int r = 0; r < 4; ++r) linv[r] = 1.f / l_[r];
#pragma unroll
  for (int dt = 0; dt < 8; ++dt)
#pragma unroll
    for (int r = 0; r < 4; ++r) {
      float v = o[dt][r] * linv[r];
      ushortT hi, lo;
      split2(v, hi, lo);
      size_t off = (size_t)(qrow + quad * 4 + r) * HID + h * HD + dt * 16 + m16;
      AOH[off] = hi;
      AOM[off] = lo;
    }
  if (m16 == 0) {
#pragma unroll
    for (int r = 0; r < 4; ++r) {
      Mb[h * SEQ + qrow + quad * 4 + r] = m_[r];   // log2 domain
      Lb[h * SEQ + qrow + quad * 4 + r] = l_[r];
    }
  }
}

// ================= MFMA colsum ============================================
__global__ __launch_bounds__(256, 3) void colsum_mfma_kernel(
    const ushortT* __restrict__ Qh, const ushortT* __restrict__ Qm, const ushortT* __restrict__ Ql,
    const ushortT* __restrict__ Kh, const ushortT* __restrict__ Km, const ushortT* __restrict__ Kl,
    const float* __restrict__ Mb, const float* __restrict__ Lb,
    float* __restrict__ HH) {
  __shared__ ushortT Qs[3][4096];   // [32 q-rows][128 d] per level, subtiled
  __shared__ float ms_s[SEQ];       // whole head m (log2 domain)
  __shared__ float ls_s[SEQ];       // whole head 1/l
  const int tid = threadIdx.x;
  const int w = tid >> 6, l = tid & 63;
  const int m16 = l & 15, quad = l >> 4;
  const int f = blockIdx.x;
  const int xcd = f & 7, g = f >> 3;
  const int h = xcd * 4 + (g >> 5);
  const int kb = g & 31;              // kb=0 is longest -> first
  const int k0 = kb * 64;
  const int kg = k0 + w * 16 + m16;   // this lane's k column

  const ushortT* Qarr[3] = {Qh, Qm, Ql};
  const ushortT* Karr[3] = {Kh, Km, Kl};

  for (int i = tid; i < SEQ; i += 256) {
    ms_s[i] = Mb[h * SEQ + i];
    ls_s[i] = 1.f / Lb[h * SEQ + i];
  }

  // K fragments (wave's 16 k-rows), direct from global, once
  short8 kf[3][4];
  {
    size_t kbase = ((size_t)h * SEQ + k0 + w * 16 + m16) * HD + quad * 8;
#pragma unroll
    for (int lv = 0; lv < 3; ++lv)
#pragma unroll
      for (int ks = 0; ks < 4; ++ks)
        kf[lv][ks] = *(const short8*)&Karr[lv][kbase + ks * 32];
  }

  float acc = 0.f;
  for (int qs = k0; qs < SEQ; qs += 32) {
    // stage Q: 3 lev x 8 chunks = 24, 6 per wave
#pragma unroll
    for (int u = 0; u < 6; ++u) {
      int c = u * 4 + w;
      int lv = c >> 3, cc = c & 7, t2 = cc >> 2, cs = cc & 3;
      const ushortT* g2 = Qarr[lv] + ((size_t)h * SEQ + qs + t2 * 16 + m16) * HD + cs * 32 + quad * 8;
      gload16(g2, &Qs[lv][t2 * 2048 + cs * 512]);
    }
    __syncthreads();

    if (qs + 31 >= k0 + w * 16) {     // skip fully-masked first tiles
#pragma unroll
      for (int t2 = 0; t2 < 2; ++t2) {
        f32x4 sA = {};
#pragma unroll
        for (int ks = 0; ks < 4; ++ks) {
          int off = t2 * 2048 + ks * 512 + quad * 128 + m16 * 8;
          short8 ah = *(const short8*)&Qs[0][off];
          short8 am = *(const short8*)&Qs[1][off];
          short8 al = *(const short8*)&Qs[2][off];
          sA = mfma16(ah, kf[0][ks], sA);
          sA = mfma16(ah, kf[1][ks], sA);
          sA = mfma16(am, kf[0][ks], sA);
          sA = mfma16(am, kf[1][ks], sA);
          sA = mfma16(ah, kf[2][ks], sA);
          sA = mfma16(al, kf[0][ks], sA);
        }
#pragma unroll
        for (int r = 0; r < 4; ++r) {
          int qq = qs + t2 * 16 + quad * 4 + r;   // global q row
          if (qq >= kg)
            acc += exp2f(sA[r] * SCALE2 - ms_s[qq]) * ls_s[qq];
        }
      }
    }
    __syncthreads();
  }

  acc += __shfl_xor(acc, 16);
  acc += __shfl_xor(acc, 32);
  if (l < 16) HH[h * SEQ + k0 + w * 16 + l] = acc;
}

// ================= fp32 fallback flash attention ==========================
__global__ __launch_bounds__(256) void flash_kernel(const float* __restrict__ Q,
                                                    const float* __restrict__ K,
                                                    const float* __restrict__ V,
                                                    float* __restrict__ AO,
                                                    float* __restrict__ Mb,
                                                    float* __restrict__ Lb) {
  __shared__ float Qs[32][136];
  __shared__ float Ks[32][136];
  __shared__ float Vs[32][136];
  __shared__ float Psm[32][33];
  __shared__ float mrow[32], lrow[32], srow[32];
  const int tid = threadIdx.x;
  const int h = blockIdx.y, qt = blockIdx.x;
  const int q0 = qt * 32;
  const float* Qh = Q + (((size_t)h * SEQ + q0) << 7);
  const float* Kh = K + ((size_t)h * SEQ << 7);
  const float* Vh = V + ((size_t)h * SEQ << 7);
  for (int i = tid; i < 1024; i += 256) {
    int row = i >> 5, c4 = (i & 31) * 4;
    *(float4*)&Qs[row][c4] = *(const float4*)&Qh[i * 4];
  }
  if (tid < 32) { mrow[tid] = -INFINITY; lrow[tid] = 0.f; }
  const int r  = tid >> 3;
  const int sl = tid & 7;
  float o_acc[16] = {};
  for (int kt = 0; kt <= qt; ++kt) {
    __syncthreads();
    for (int i = tid; i < 1024; i += 256) {
      int row = i >> 5, c4 = (i & 31) * 4;
      *(float4*)&Ks[row][c4] = *(const float4*)&Kh[(size_t)kt * 4096 + i * 4];
      *(float4*)&Vs[row][c4] = *(const float4*)&Vh[(size_t)kt * 4096 + i * 4];
    }
    __syncthreads();
    float sacc[4] = {};
#pragma unroll 8
    for (int c = 0; c < 128; c += 4) {
      float4 qv = *(const float4*)&Qs[r][c];
#pragma unroll
      for (int j = 0; j < 4; ++j) {
        float4 kv = *(const float4*)&Ks[sl + 8 * j][c];
        sacc[j] = fmaf(qv.x, kv.x, sacc[j]);
        sacc[j] = fmaf(qv.y, kv.y, sacc[j]);
        sacc[j] = fmaf(qv.z, kv.z, sacc[j]);
        sacc[j] = fmaf(qv.w, kv.w, sacc[j]);
      }
    }
    const int qg = q0 + r;
#pragma unroll
    for (int j = 0; j < 4; ++j) {
      int kg = kt * 32 + sl + 8 * j;
      Psm[r][sl + 8 * j] = (kg <= qg) ? (sacc[j] * RSQRT_D) : -INFINITY;
    }
    __syncthreads();
    if (tid < 32) {
      int rr = tid;
      float mold = mrow[rr];
      float mt = mold;
#pragma unroll
      for (int k2 = 0; k2 < 32; ++k2) mt = fmaxf(mt, Psm[rr][k2]);
      float sc = expf(mold - mt);
      float lsv = 0.f;
#pragma unroll
      for (int k2 = 0; k2 < 32; ++k2) {
        float p = expf(Psm[rr][k2] - mt);
        Psm[rr][k2] = p;
        lsv += p;
      }
      mrow[rr] = mt;
      lrow[rr] = lrow[rr] * sc + lsv;
      srow[rr] = sc;
    }
    __syncthreads();
    float sc = srow[r];
#pragma unroll
    for (int d2 = 0; d2 < 16; ++d2) o_acc[d2] *= sc;
#pragma unroll 4
    for (int k2 = 0; k2 < 32; ++k2) {
      float p = Psm[r][k2];
      float4 v0 = *(const float4*)&Vs[k2][sl * 4];
      float4 v1 = *(const float4*)&Vs[k2][sl * 4 + 32];
      float4 v2 = *(const float4*)&Vs[k2][sl * 4 + 64];
      float4 v3 = *(const float4*)&Vs[k2][sl * 4 + 96];
      o_acc[0]  = fmaf(p, v0.x, o_acc[0]);  o_acc[1]  = fmaf(p, v0.y, o_acc[1]);
      o_acc[2]  = fmaf(p, v0.z, o_acc[2]);  o_acc[3]  = fmaf(p, v0.w, o_acc[3]);
      o_acc[4]  = fmaf(p, v1.x, o_acc[4]);  o_acc[5]  = fmaf(p, v1.y, o_acc[5]);
      o_acc[6]  = fmaf(p, v1.z, o_acc[6]);  o_acc[7]  = fmaf(p, v1.w, o_acc[7]);
      o_acc[8]  = fmaf(p, v2.x, o_acc[8]);  o_acc[9]  = fmaf(p, v2.y, o_acc[9]);
      o_acc[10] = fmaf(p, v2.z, o_acc[10]); o_acc[11] = fmaf(p, v2.w, o_acc[11]);
      o_acc[12] = fmaf(p, v3.x, o_acc[12]); o_acc[13] = fmaf(p, v3.y, o_acc[13]);
      o_acc[14] = fmaf(p, v3.z, o_acc[14]); o_acc[15] = fmaf(p, v3.w, o_acc[15]);
    }
  }
  float linv = 1.f / lrow[r];
  int s = q0 + r;
  float* orow = &AO[(size_t)s * HID + h * 128];
#pragma unroll
  for (int m = 0; m < 4; ++m) {
    float4 wv;
    wv.x = o_acc[4 * m + 0] * linv; wv.y = o_acc[4 * m + 1] * linv;
    wv.z = o_acc[4 * m + 2] * linv; wv.w = o_acc[4 * m + 3] * linv;
    *(float4*)&orow[sl * 4 + 32 * m] = wv;
  }
  if (tid < 32) {
    Mb[h * SEQ + q0 + tid] = mrow[tid];
    Lb[h * SEQ + q0 + tid] = lrow[tid];
  }
}

// ================= fp32 fallback colsum ===================================
__global__ __launch_bounds__(256) void colsum_kernel(const float* __restrict__ Q,
                                                     const float* __restrict__ K,
                                                     const float* __restrict__ Mb,
                                                     const float* __restrict__ Lb,
                                                     float* __restrict__ HH) {
  __shared__ float Ks[32][136];
  __shared__ float Qs[32][136];
  __shared__ float ms[32], ls[32];
  __shared__ float part[32][9];
  const int tid = threadIdx.x;
  const int h = blockIdx.y, kt = blockIdx.x;
  const int k0 = kt * 32;
  const float* Kh = K + ((size_t)h * SEQ << 7);
  const float* Qh = Q + ((size_t)h * SEQ << 7);
  for (int i = tid; i < 1024; i += 256) {
    int row = i >> 5, c4 = (i & 31) * 4;
    *(float4*)&Ks[row][c4] = *(const float4*)&Kh[(size_t)k0 * 128 + i * 4];
  }
  const int c = tid >> 3;
  const int qsl = tid & 7;
  const int kg = k0 + c;
  float acc = 0.f;
  for (int qt = kt; qt < NKT; ++qt) {
    __syncthreads();
    for (int i = tid; i < 1024; i += 256) {
      int row = i >> 5, c4 = (i & 31) * 4;
      *(float4*)&Qs[row][c4] = *(const float4*)&Qh[(size_t)qt * 4096 + i * 4];
    }
    if (tid < 32) {
      ms[tid] = Mb[h * SEQ + qt * 32 + tid];
      ls[tid] = 1.f / Lb[h * SEQ + qt * 32 + tid];
    }
    __syncthreads();
    float dacc[4] = {};
#pragma unroll 8
    for (int cc = 0; cc < 128; cc += 4) {
      float4 kv = *(const float4*)&Ks[c][cc];
#pragma unroll
      for (int j = 0; j < 4; ++j) {
        float4 qv = *(const float4*)&Qs[qsl + 8 * j][cc];
        dacc[j] = fmaf(qv.x, kv.x, dacc[j]);
        dacc[j] = fmaf(qv.y, kv.y, dacc[j]);
        dacc[j] = fmaf(qv.z, kv.z, dacc[j]);
        dacc[j] = fmaf(qv.w, kv.w, dacc[j]);
      }
    }
#pragma unroll
    for (int j = 0; j < 4; ++j) {
      int qr = qsl + 8 * j;
      int qg = qt * 32 + qr;
      if (qg >= kg)
        acc += expf(dacc[j] * RSQRT_D - ms[qr]) * ls[qr];
    }
  }
  part[c][qsl] = acc;
  __syncthreads();
  if (qsl == 0) {
    float ssum = 0.f;
#pragma unroll
    for (int t2 = 0; t2 < 8; ++t2) ssum += part[c][t2];
    HH[h * SEQ + k0 + c] = ssum;
  }
}

// ================= top-k ===================================================
__global__ __launch_bounds__(256) void topk_kernel(const float* __restrict__ HH,
                                                   int* __restrict__ keep) {
  __shared__ float vals[SELN];
  __shared__ float rv[256];
  __shared__ int   ri[256];
  __shared__ int   sel[HHSZ];
  const int h = blockIdx.x, tid = threadIdx.x;
  for (int i = tid; i < SELN; i += 256) vals[i] = HH[h * SEQ + i];
  __syncthreads();
  for (int it = 0; it < HHSZ; ++it) {
    float bv = -INFINITY; int bi = 0x7fffffff;
    for (int i = tid; i < SELN; i += 256) {
      float v = vals[i];
      if (v > bv || (v == bv && i < bi)) { bv = v; bi = i; }
    }
    rv[tid] = bv; ri[tid] = bi;
    __syncthreads();
    for (int sft = 128; sft > 0; sft >>= 1) {
      if (tid < sft) {
        if (rv[tid + sft] > rv[tid] ||
            (rv[tid + sft] == rv[tid] && ri[tid + sft] < ri[tid])) {
          rv[tid] = rv[tid + sft]; ri[tid] = ri[tid + sft];
        }
      }
      __syncthreads();
    }
    if (tid == 0) { sel[it] = ri[0]; vals[ri[0]] = -INFINITY; }
    __syncthreads();
  }
  for (int ph = 0; ph < HHSZ; ++ph) {
    int i = (ph & 1) + 2 * tid;
    if (i + 1 < HHSZ) {
      int a = sel[i], b = sel[i + 1];
      if (a > b) { sel[i] = b; sel[i + 1] = a; }
    }
    __syncthreads();
  }
  for (int i = tid; i < HHSZ; i += 256) keep[h * CACHE + i] = sel[i];
  for (int i = tid; i < RECENT; i += 256) keep[h * CACHE + HHSZ + i] = SELN + i;
}

// ================= gather (optionally applies RoPE to K rows) =============
__global__ void gather_kernel(const float* __restrict__ K, const float* __restrict__ V,
                              const float* __restrict__ HH, const int* __restrict__ keep,
                              const int* __restrict__ pos,
                              const float* __restrict__ cosT, const float* __restrict__ sinT,
                              float* __restrict__ k_out, float* __restrict__ v_out,
                              float* __restrict__ hh_out, int rope_k) {
  __shared__ float kr[128];
  const int j = blockIdx.x;
  const int h = blockIdx.y;
  const int d = threadIdx.x;
  const int idx = keep[h * CACHE + j];
  size_t src = (((size_t)h * SEQ + idx) << 7) + d;
  size_t dst = (((size_t)h * CACHE + j) << 7) + d;
  float kv = K[src];
  if (rope_k) {
    kr[d] = kv;
    __syncthreads();
    int p = pos[idx];
    float c = cosT[p * 64 + (d & 63)];
    float sn = sinT[p * 64 + (d & 63)];
    float xo = kr[d ^ 64];
    kv = kv * c + ((d < 64) ? -xo : xo) * sn;
  }
  k_out[dst] = kv;
  v_out[dst] = V[src];
  if (d == 0) hh_out[h * CACHE + j] = HH[h * SEQ + idx];
}

// ================= launch ==================================================
extern "C" void kernel_launch(void* const* d_in, const int* in_sizes, int n_in,
                              void* d_out, int out_size, void* d_ws, size_t ws_size,
                              hipStream_t stream) {
  (void)in_sizes; (void)n_in; (void)out_size;
  const float* hs  = (const float*)d_in[0];
  const int*   pos = (const int*)d_in[1];
  const float* Wq  = (const float*)d_in[2];
  const float* Wk  = (const float*)d_in[3];
  const float* Wv  = (const float*)d_in[4];
  const float* Wo  = (const float*)d_in[5];

  float* out = (float*)d_out;                 // [2048][4096]
  float* khh = out + (size_t)SEQ * HID;       // [32][768][128]
  float* vhh = khh + (size_t)NH * CACHE * HD;
  float* hhk = vhh + (size_t)NH * CACHE * HD; // [32][768]

  char* p = (char*)d_ws;
  auto alloc = [&](size_t bytes) { char* r = p; p += (bytes + 255) & ~(size_t)255; return r; };

  float* Qw   = (float*)alloc((size_t)NH * SEQ * HD * 4);
  float* Kw   = (float*)alloc((size_t)NH * SEQ * HD * 4);
  float* Vw   = (float*)alloc((size_t)NH * SEQ * HD * 4);
  float* AO   = (float*)alloc((size_t)SEQ * HID * 4);   // mfma path: AO bf16 splits live here
  float* Mb   = (float*)alloc((size_t)NH * SEQ * 4);
  float* Lb   = (float*)alloc((size_t)NH * SEQ * 4);
  float* HH   = (float*)alloc((size_t)NH * SEQ * 4);
  float* cosT = (float*)alloc((size_t)SEQ * 64 * 4);
  float* sinT = (float*)alloc((size_t)SEQ * 64 * 4);
  int*   keep = (int*)alloc((size_t)NH * CACHE * 4);
  // bf16 split buffers
  ushortT* hsH = (ushortT*)alloc((size_t)SEQ * HID * 2);
  ushortT* hsM = (ushortT*)alloc((size_t)SEQ * HID * 2);
  ushortT* hsL = (ushortT*)alloc((size_t)SEQ * HID * 2);
  ushortT* WH  = (ushortT*)alloc((size_t)HID * HID * 2);
  ushortT* WM  = (ushortT*)alloc((size_t)HID * HID * 2);
  ushortT* WL  = (ushortT*)alloc((size_t)HID * HID * 2);
  const size_t needed = (size_t)(p - (char*)d_ws);
  const bool use_mfma = ws_size >= needed;

  const dim3 ggrid(32, 16);
  const int n4hs = SEQ * HID / 4;    // 2097152
  const int n4w  = HID * HID / 4;    // 4194304

  rope_tables_kernel<<<SEQ, 64, 0, stream>>>(cosT, sinT);

  if (use_mfma) {
    split3_kernel<<<n4hs / 256, 256, 0, stream>>>(hs, hsH, hsM, hsL, n4hs);
    split3_kernel<<<n4w / 256, 256, 0, stream>>>(Wq, WH, WM, WL, n4w);
    gemm_mfma<3, 1><<<ggrid, 256, 0, stream>>>(hsH, hsM, hsL, WH, WM, WL, Qw);
    split3_kernel<<<n4w / 256, 256, 0, stream>>>(Wk, WH, WM, WL, n4w);
    gemm_mfma<3, 1><<<ggrid, 256, 0, stream>>>(hsH, hsM, hsL, WH, WM, WL, Kw);
    split2_kernel<<<n4w / 256, 256, 0, stream>>>(Wv, WH, WM, n4w);
    gemm_mfma<2, 1><<<ggrid, 256, 0, stream>>>(hsH, hsM, nullptr, WH, WM, nullptr, Vw);

    // RoPE fused into the Q/K split passes (Qw/Kw fp32 stay un-roped;
    // gather applies RoPE to the kept K rows).
    const size_t QKOFF = (size_t)NH * SEQ * HD;   // ushorts
    const int n4qk = NH * SEQ * HD / 4;
    split3_rope_kernel<<<n4qk / 256, 256, 0, stream>>>(Qw, pos, cosT, sinT, WH, WM, WL, n4qk);
    split3_rope_kernel<<<n4qk / 256, 256, 0, stream>>>(Kw, pos, cosT, sinT,
                                                       WH + QKOFF, WM + QKOFF, WL + QKOFF, n4qk);
    split2t_kernel<<<dim3(64, 4, 32), 256, 0, stream>>>(Vw, hsH, hsM);

    ushortT* AOH = (ushortT*)AO;
    ushortT* AOM = AOH + (size_t)SEQ * HID;
    flash_mfma_kernel<<<1024, 256, 0, stream>>>(
        WH, WM, WL, WH + QKOFF, WM + QKOFF, WL + QKOFF, hsH, hsM, AOH, AOM, Mb, Lb);
    colsum_mfma_kernel<<<1024, 256, 0, stream>>>(
        WH, WM, WL, WH + QKOFF, WM + QKOFF, WL + QKOFF, Mb, Lb, HH);

    split2_kernel<<<n4w / 256, 256, 0, stream>>>(Wo, WH, WM, n4w);
    gemm_mfma<2, 0><<<ggrid, 256, 0, stream>>>(AOH, AOM, nullptr, WH, WM, nullptr, out);

    topk_kernel<<<NH, 256, 0, stream>>>(HH, keep);
    gather_kernel<<<dim3(CACHE, NH), 128, 0, stream>>>(Kw, Vw, HH, keep, pos, cosT, sinT,
                                                       khh, vhh, hhk, 1);
  } else {
    gemm_nt<1><<<ggrid, 256, 0, stream>>>(hs, Wq, Qw);
    gemm_nt<1><<<ggrid, 256, 0, stream>>>(hs, Wk, Kw);
    gemm_nt<1><<<ggrid, 256, 0, stream>>>(hs, Wv, Vw);
    rope_apply_kernel<<<dim3(SEQ, NH, 2), 128, 0, stream>>>(Qw, Kw, pos, cosT, sinT);
    flash_kernel<<<dim3(NKT, NH), 256, 0, stream>>>(Qw, Kw, Vw, AO, Mb, Lb);
    colsum_kernel<<<dim3(NKT, NH), 256, 0, stream>>>(Qw, Kw, Mb, Lb, HH);
    gemm_nt<0><<<ggrid, 256, 0, stream>>>(AO, Wo, out);
    topk_kernel<<<NH, 256, 0, stream>>>(HH, keep);
    gather_kernel<<<dim3(CACHE, NH), 128, 0, stream>>>(Kw, Vw, HH, keep, pos, cosT, sinT,
                                                       khh, vhh, hhk, 0);
  }
}

// Round 3
// 2164.809 us; speedup vs baseline: 2.1992x; 1.2343x over previous
//
#include <hip/hip_runtime.h>
#include <hip/hip_bf16.h>
#include <math.h>

#define HID 4096
#define NH 32
#define HD 128
#define SEQ 2048
#define NKT 64
#define HHSZ 256
#define RECENT 512
#define CACHE 768
#define SELN 1536
#define RSQRT_D 0.08838834764831845f
// RSQRT_D * log2(e): scores scaled into log2 domain for exp2-based softmax
#define SCALE2 0.12751749522423355f

typedef unsigned short ushortT;
typedef __attribute__((ext_vector_type(8))) short short8;
typedef __attribute__((ext_vector_type(4))) float f32x4;

// ================= bf16 split helpers =====================================
__device__ __forceinline__ ushortT f2b(float f) {
  union { __hip_bfloat16 h; ushortT u; } v;
  v.h = __float2bfloat16(f);
  return v.u;
}
__device__ __forceinline__ float b2f(ushortT u) {
  union { unsigned int i; float f; } v;
  v.i = ((unsigned int)u) << 16;
  return v.f;
}
__device__ __forceinline__ void split3(float x, ushortT& h, ushortT& m, ushortT& l) {
  h = f2b(x);
  float r = x - b2f(h);
  m = f2b(r);
  float r2 = r - b2f(m);
  l = f2b(r2);
}
__device__ __forceinline__ void split2(float x, ushortT& h, ushortT& l) {
  h = f2b(x);
  l = f2b(x - b2f(h));
}

__global__ __launch_bounds__(256) void split3_kernel(const float* __restrict__ X,
    ushortT* __restrict__ o0, ushortT* __restrict__ o1, ushortT* __restrict__ o2, int n4) {
  int i = blockIdx.x * 256 + threadIdx.x;
  if (i >= n4) return;
  float4 x = ((const float4*)X)[i];
  ushort4 a, b, c;
  split3(x.x, a.x, b.x, c.x);
  split3(x.y, a.y, b.y, c.y);
  split3(x.z, a.z, b.z, c.z);
  split3(x.w, a.w, b.w, c.w);
  ((ushort4*)o0)[i] = a;
  ((ushort4*)o1)[i] = b;
  ((ushort4*)o2)[i] = c;
}
__global__ __launch_bounds__(256) void split2_kernel(const float* __restrict__ X,
    ushortT* __restrict__ o0, ushortT* __restrict__ o1, int n4) {
  int i = blockIdx.x * 256 + threadIdx.x;
  if (i >= n4) return;
  float4 x = ((const float4*)X)[i];
  ushort4 a, b;
  split2(x.x, a.x, b.x);
  split2(x.y, a.y, b.y);
  split2(x.z, a.z, b.z);
  split2(x.w, a.w, b.w);
  ((ushort4*)o0)[i] = a;
  ((ushort4*)o1)[i] = b;
}

// split3 with fused RoPE: X is [h][s][128] fp32 (un-roped); outputs roped splits.
__global__ __launch_bounds__(256) void split3_rope_kernel(const float* __restrict__ X,
    const int* __restrict__ pos, const float* __restrict__ cosT, const float* __restrict__ sinT,
    ushortT* __restrict__ o0, ushortT* __restrict__ o1, ushortT* __restrict__ o2, int n4) {
  int i = blockIdx.x * 256 + threadIdx.x;
  if (i >= n4) return;
  float4 x = ((const float4*)X)[i];
  float4 y = ((const float4*)X)[i ^ 16];   // partner half (d ^ 64)
  int d4 = i & 31;                          // float4 index in 128-elem row
  int row = i >> 5;                         // h*SEQ + s
  int s = row & (SEQ - 1);
  int p = pos[s];
  int d = d4 * 4;
  float4 c = *(const float4*)&cosT[p * 64 + (d & 63)];
  float4 sn = *(const float4*)&sinT[p * 64 + (d & 63)];
  float sg = (d < 64) ? -1.f : 1.f;
  float4 v;
  v.x = x.x * c.x + sg * y.x * sn.x;
  v.y = x.y * c.y + sg * y.y * sn.y;
  v.z = x.z * c.z + sg * y.z * sn.z;
  v.w = x.w * c.w + sg * y.w * sn.w;
  ushort4 a, b, cc;
  split3(v.x, a.x, b.x, cc.x);
  split3(v.y, a.y, b.y, cc.y);
  split3(v.z, a.z, b.z, cc.z);
  split3(v.w, a.w, b.w, cc.w);
  ((ushort4*)o0)[i] = a;
  ((ushort4*)o1)[i] = b;
  ((ushort4*)o2)[i] = cc;
}

// split V [h][s][128] fp32 -> transposed bf16 levels [h][128][2048]
__global__ __launch_bounds__(256) void split2t_kernel(const float* __restrict__ V,
    ushortT* __restrict__ oH, ushortT* __restrict__ oL) {
  __shared__ float T[32][33];
  const int h = blockIdx.z, s0 = blockIdx.x * 32, d0 = blockIdx.y * 32;
  const int t = threadIdx.x;
  {
    int sr = t >> 3, dc = (t & 7) * 4;
    float4 v = *(const float4*)&V[(((size_t)h * SEQ + s0 + sr) << 7) + d0 + dc];
    T[sr][dc + 0] = v.x; T[sr][dc + 1] = v.y;
    T[sr][dc + 2] = v.z; T[sr][dc + 3] = v.w;
  }
  __syncthreads();
  int dr = t >> 3, sc = (t & 7) * 4;
  ushort4 a, b;
  split2(T[sc + 0][dr], a.x, b.x);
  split2(T[sc + 1][dr], a.y, b.y);
  split2(T[sc + 2][dr], a.z, b.z);
  split2(T[sc + 3][dr], a.w, b.w);
  size_t dst = ((size_t)h * HD + d0 + dr) * SEQ + s0 + sc;
  *(ushort4*)&oH[dst] = a;
  *(ushort4*)&oL[dst] = b;
}

// ================= async global->LDS ======================================
__device__ __forceinline__ void gload16(const void* g, void* lds) {
  __builtin_amdgcn_global_load_lds(
      (const __attribute__((address_space(1))) unsigned int*)g,
      (__attribute__((address_space(3))) unsigned int*)lds, 16, 0, 0);
}

__device__ __forceinline__ f32x4 mfma16(short8 a, short8 b, f32x4 c) {
  return __builtin_amdgcn_mfma_f32_16x16x32_bf16(a, b, c, 0, 0, 0);
}

// ================= split-bf16 MFMA GEMM  C = A * B^T ======================
template<int LEV, int MODE>
__global__ __launch_bounds__(256, 2) void gemm_mfma(
    const ushortT* __restrict__ A0, const ushortT* __restrict__ A1, const ushortT* __restrict__ A2,
    const ushortT* __restrict__ B0, const ushortT* __restrict__ B1, const ushortT* __restrict__ B2,
    float* __restrict__ C) {
  __shared__ ushortT As[LEV][4096];
  __shared__ ushortT Bs[LEV][4096];
  const int tid = threadIdx.x;
  const int w = tid >> 6, l = tid & 63;
  const int m16 = l & 15, quad = l >> 4;
  const int wr = w >> 1, wc = w & 1;
  // XCD-chunked bijective swizzle: 64 consecutive blocks per XCD share A-panels
  const int id = blockIdx.y * 32 + blockIdx.x;          // 0..511
  const int nid = (id & 7) * 64 + (id >> 3);
  const int m0 = (nid >> 5) * 128, n0 = (nid & 31) * 128;
  const ushortT* Aarr[3] = {A0, A1, A2};
  const ushortT* Barr[3] = {B0, B1, B2};
  const size_t laneA = (size_t)(m0 + m16) * HID + quad * 8;
  const size_t laneB = (size_t)(n0 + m16) * HID + quad * 8;

  f32x4 acc[4][4] = {};

  for (int k0 = 0; k0 < HID; k0 += 32) {
#pragma unroll
    for (int u = 0; u < LEV * 4; ++u) {
      int t = u * 4 + w;
      int p = t >> 3, q = t & 7;
      const ushortT* g;
      ushortT* s;
      if (p < LEV) {
        g = Aarr[p] + laneA + (size_t)q * 16 * HID + k0;
        s = &As[p][q * 512];
      } else {
        g = Barr[p - LEV] + laneB + (size_t)q * 16 * HID + k0;
        s = &Bs[p - LEV][q * 512];
      }
      gload16(g, s);
    }
    __syncthreads();

    short8 af[LEV][4], bf[LEV][4];
#pragma unroll
    for (int v = 0; v < LEV; ++v)
#pragma unroll
      for (int i = 0; i < 4; ++i) {
        af[v][i] = *(const short8*)&As[v][(wr * 4 + i) * 512 + quad * 128 + m16 * 8];
        bf[v][i] = *(const short8*)&Bs[v][(wc * 4 + i) * 512 + quad * 128 + m16 * 8];
      }
#pragma unroll
    for (int i = 0; i < 4; ++i)
#pragma unroll
      for (int j = 0; j < 4; ++j) {
        acc[i][j] = mfma16(af[0][i], bf[0][j], acc[i][j]);
        acc[i][j] = mfma16(af[0][i], bf[1][j], acc[i][j]);
        acc[i][j] = mfma16(af[1][i], bf[0][j], acc[i][j]);
        if (LEV == 3) {
          acc[i][j] = mfma16(af[1][i], bf[1][j], acc[i][j]);
          acc[i][j] = mfma16(af[0][i], bf[2][j], acc[i][j]);
          acc[i][j] = mfma16(af[2][i], bf[0][j], acc[i][j]);
        }
      }
    __syncthreads();
  }

  const int row0 = m0 + wr * 64;
  const int col0 = n0 + wc * 64;
#pragma unroll
  for (int i = 0; i < 4; ++i)
#pragma unroll
    for (int j = 0; j < 4; ++j) {
#pragma unroll
      for (int r = 0; r < 4; ++r) {
        int row = row0 + i * 16 + quad * 4 + r;
        int col = col0 + j * 16 + m16;
        float v = acc[i][j][r];
        if (MODE == 0) {
          C[(size_t)row * HID + col] = v;
        } else {
          int h = col >> 7, d = col & 127;
          C[(((size_t)h * SEQ + row) << 7) + d] = v;
        }
      }
    }
}

// ================= fp32 fallback GEMM =====================================
template<int MODE>
__global__ __launch_bounds__(256) void gemm_nt(const float* __restrict__ A,
                                               const float* __restrict__ B,
                                               float* __restrict__ C) {
  __shared__ float Asm[16][132];
  __shared__ float Bsm[16][132];
  const int tid = threadIdx.x;
  const int tx = tid & 15, ty = tid >> 4;
  const int m0 = blockIdx.y * 128, n0 = blockIdx.x * 128;
  float acc[8][8] = {};
  for (int k0 = 0; k0 < HID; k0 += 16) {
#pragma unroll
    for (int lp = 0; lp < 2; ++lp) {
      int i = tid + lp * 256;
      int row = i >> 2;
      int col = (i & 3) * 4;
      float4 av = *(const float4*)&A[(size_t)(m0 + row) * HID + k0 + col];
      Asm[col + 0][row] = av.x; Asm[col + 1][row] = av.y;
      Asm[col + 2][row] = av.z; Asm[col + 3][row] = av.w;
      float4 bv = *(const float4*)&B[(size_t)(n0 + row) * HID + k0 + col];
      Bsm[col + 0][row] = bv.x; Bsm[col + 1][row] = bv.y;
      Bsm[col + 2][row] = bv.z; Bsm[col + 3][row] = bv.w;
    }
    __syncthreads();
#pragma unroll
    for (int kk = 0; kk < 16; ++kk) {
      float a[8], b[8];
      *(float4*)&a[0] = *(const float4*)&Asm[kk][ty * 4];
      *(float4*)&a[4] = *(const float4*)&Asm[kk][64 + ty * 4];
      *(float4*)&b[0] = *(const float4*)&Bsm[kk][tx * 4];
      *(float4*)&b[4] = *(const float4*)&Bsm[kk][64 + tx * 4];
#pragma unroll
      for (int i2 = 0; i2 < 8; ++i2)
#pragma unroll
        for (int j2 = 0; j2 < 8; ++j2)
          acc[i2][j2] = fmaf(a[i2], b[j2], acc[i2][j2]);
    }
    __syncthreads();
  }
#pragma unroll
  for (int i2 = 0; i2 < 8; ++i2) {
    int s = m0 + ((i2 < 4) ? (ty * 4 + i2) : (64 + ty * 4 + i2 - 4));
#pragma unroll
    for (int j2 = 0; j2 < 8; ++j2) {
      int o = n0 + ((j2 < 4) ? (tx * 4 + j2) : (64 + tx * 4 + j2 - 4));
      float v = acc[i2][j2];
      if (MODE == 0) {
        C[(size_t)s * HID + o] = v;
      } else {
        int h = o >> 7, d = o & 127;
        C[(((size_t)h * SEQ + s) << 7) + d] = v;
      }
    }
  }
}

// ================= RoPE ====================================================
__global__ void rope_tables_kernel(float* __restrict__ cosT, float* __restrict__ sinT) {
  int t = blockIdx.x;
  int i = threadIdx.x;  // 0..63
  double inv = pow(10000.0, -((double)(2 * i)) / 128.0);
  float ang = (float)t * (float)inv;
  cosT[t * 64 + i] = cosf(ang);
  sinT[t * 64 + i] = sinf(ang);
}

// fallback-path rope (in-place on fp32 Q/K)
__global__ void rope_apply_kernel(float* __restrict__ Q, float* __restrict__ K,
                                  const int* __restrict__ pos,
                                  const float* __restrict__ cosT,
                                  const float* __restrict__ sinT) {
  int d = threadIdx.x;           // 0..127
  int s = blockIdx.x;
  int h = blockIdx.y;
  float* X = blockIdx.z ? K : Q;
  float* row = X + (((size_t)h * SEQ + s) << 7);
  int p = pos[s];
  int i = d & 63;
  float c = cosT[p * 64 + i];
  float sn = sinT[p * 64 + i];
  float x  = row[d];
  float xo = row[(d < 64) ? (d + 64) : (d - 64)];
  float rot = (d < 64) ? -xo : xo;
  __syncthreads();
  row[d] = x * c + rot * sn;
}

// ================= MFMA flash attention ===================================
// Block: 4 waves, 64 q-rows. Softmax in log2 domain (exp2), defer-rescale.
// Grid 1024 flat: swizzled so all heads' biggest q-blocks launch first and
// each XCD co-hosts a 4-head group (K/V L2-resident).
__global__ __launch_bounds__(256, 3) void flash_mfma_kernel(
    const ushortT* __restrict__ Qh, const ushortT* __restrict__ Qm, const ushortT* __restrict__ Ql,
    const ushortT* __restrict__ Kh, const ushortT* __restrict__ Km, const ushortT* __restrict__ Kl,
    const ushortT* __restrict__ VtH, const ushortT* __restrict__ VtL,
    ushortT* __restrict__ AOH, ushortT* __restrict__ AOM,
    float* __restrict__ Mb, float* __restrict__ Lb) {
  __shared__ ushortT Ks[3][4096];   // [32 k-rows][128 d] per level, subtiled
  __shared__ ushortT Vts[2][4096];  // [128 d-rows][32 s] per level, subtiled
  __shared__ ushortT Ps[4][2][512]; // per-wave P tile [16 q][32 k], subtiled
  const int tid = threadIdx.x;
  const int w = tid >> 6, l = tid & 63;
  const int m16 = l & 15, quad = l >> 4;
  const int f = blockIdx.x;
  const int xcd = f & 7, g = f >> 3;
  const int h = xcd * 4 + (g >> 5);   // 4 heads per XCD group
  const int qb = 31 - (g & 31);       // biggest blocks first everywhere
  const int q0 = qb * 64;
  const int qrow = q0 + w * 16;

  const ushortT* Qarr[3] = {Qh, Qm, Ql};
  const ushortT* Karr[3] = {Kh, Km, Kl};
  const ushortT* Varr[2] = {VtH, VtL};

  // Q fragments in registers (wave-private, loaded once)
  short8 qf[3][4];
  {
    size_t qbase = ((size_t)h * SEQ + qrow + m16) * HD + quad * 8;
#pragma unroll
    for (int lv = 0; lv < 3; ++lv)
#pragma unroll
      for (int ks = 0; ks < 4; ++ks)
        qf[lv][ks] = *(const short8*)&Qarr[lv][qbase + ks * 32];
  }

  f32x4 o[8] = {};
  float m_[4] = {-INFINITY, -INFINITY, -INFINITY, -INFINITY};
  float l_[4] = {0.f, 0.f, 0.f, 0.f};

  const int kt_max = 2 * qb + 1;
  const int my_ktmax = 2 * qb + ((w >= 2) ? 1 : 0);   // waves 0,1 skip last tile
  for (int kt = 0; kt <= kt_max; ++kt) {
    // ---- stage K (3 lev) + Vt (2 lev): 40 chunks of 1KB, 10 per wave ----
#pragma unroll
    for (int u = 0; u < 10; ++u) {
      int c = u * 4 + w;
      const ushortT* g2;
      ushortT* s;
      if (c < 24) {
        int lv = c >> 3, cc = c & 7, st = cc >> 2, cs = cc & 3;
        g2 = Karr[lv] + ((size_t)h * SEQ + kt * 32 + st * 16 + m16) * HD + cs * 32 + quad * 8;
        s = &Ks[lv][st * 2048 + cs * 512];
      } else {
        int c2 = c - 24, lv = c2 >> 3, dt = c2 & 7;
        g2 = Varr[lv] + ((size_t)h * HD + dt * 16 + m16) * SEQ + kt * 32 + quad * 8;
        s = &Vts[lv][dt * 512];
      }
      gload16(g2, s);
    }
    __syncthreads();

    if (kt <= my_ktmax) {
      // ---- QK^T: S[16 q][32 k], 6-product split3 ----
      f32x4 sA[2] = {};
#pragma unroll
      for (int t2 = 0; t2 < 2; ++t2)
#pragma unroll
        for (int ks = 0; ks < 4; ++ks) {
          int off = t2 * 2048 + ks * 512 + quad * 128 + m16 * 8;
          short8 bh = *(const short8*)&Ks[0][off];
          short8 bm = *(const short8*)&Ks[1][off];
          short8 bl = *(const short8*)&Ks[2][off];
          sA[t2] = mfma16(qf[0][ks], bh, sA[t2]);
          sA[t2] = mfma16(qf[0][ks], bm, sA[t2]);
          sA[t2] = mfma16(qf[1][ks], bh, sA[t2]);
          sA[t2] = mfma16(qf[1][ks], bm, sA[t2]);
          sA[t2] = mfma16(qf[0][ks], bl, sA[t2]);
          sA[t2] = mfma16(qf[2][ks], bh, sA[t2]);
        }

      // ---- scale (log2 domain) + causal mask (per-wave tight) ----
      const bool need_mask = (kt * 32 + 31 > qrow);
#pragma unroll
      for (int t2 = 0; t2 < 2; ++t2)
#pragma unroll
        for (int r = 0; r < 4; ++r) {
          float v = sA[t2][r] * SCALE2;
          if (need_mask) {
            int kg = kt * 32 + t2 * 16 + m16;
            int qg = qrow + quad * 4 + r;
            if (kg > qg) v = -INFINITY;
          }
          sA[t2][r] = v;
        }

      // ---- online softmax, wave-parallel, defer-rescale ----
      float tmax[4];
#pragma unroll
      for (int r = 0; r < 4; ++r) tmax[r] = fmaxf(sA[0][r], sA[1][r]);
#pragma unroll
      for (int msk = 1; msk <= 8; msk <<= 1)
#pragma unroll
        for (int r = 0; r < 4; ++r)
          tmax[r] = fmaxf(tmax[r], __shfl_xor(tmax[r], msk));

      bool small = true;
#pragma unroll
      for (int r = 0; r < 4; ++r) small = small && (tmax[r] <= m_[r] + 11.0f);
      if (!__all(small)) {
#pragma unroll
        for (int r = 0; r < 4; ++r) {
          float mn = fmaxf(m_[r], tmax[r]);
          float sc = exp2f(m_[r] - mn);
          m_[r] = mn;
          l_[r] *= sc;
#pragma unroll
          for (int dt = 0; dt < 8; ++dt) o[dt][r] *= sc;
        }
      }
      float rs[4];
#pragma unroll
      for (int r = 0; r < 4; ++r) {
        float p0 = exp2f(sA[0][r] - m_[r]);
        float p1 = exp2f(sA[1][r] - m_[r]);
        sA[0][r] = p0; sA[1][r] = p1;
        rs[r] = p0 + p1;
      }
#pragma unroll
      for (int msk = 1; msk <= 8; msk <<= 1)
#pragma unroll
        for (int r = 0; r < 4; ++r) rs[r] += __shfl_xor(rs[r], msk);
#pragma unroll
      for (int r = 0; r < 4; ++r) l_[r] += rs[r];

      // ---- P -> bf16 split2, relayout via wave-private LDS ----
#pragma unroll
      for (int t2 = 0; t2 < 2; ++t2)
#pragma unroll
        for (int r = 0; r < 4; ++r) {
          float p = sA[t2][r];
          ushortT ph = f2b(p);
          ushortT pl = f2b(p - b2f(ph));
          int off = (t2 * 2 + (m16 >> 3)) * 128 + (quad * 4 + r) * 8 + (m16 & 7);
          Ps[w][0][off] = ph;
          Ps[w][1][off] = pl;
        }

      // ---- PV: O += P * V, 3-product split2 ----
      short8 pah = *(const short8*)&Ps[w][0][quad * 128 + m16 * 8];
      short8 pal = *(const short8*)&Ps[w][1][quad * 128 + m16 * 8];
#pragma unroll
      for (int dt = 0; dt < 8; ++dt) {
        int off = dt * 512 + quad * 128 + m16 * 8;
        short8 vh = *(const short8*)&Vts[0][off];
        short8 vl = *(const short8*)&Vts[1][off];
        o[dt] = mfma16(pah, vh, o[dt]);
        o[dt] = mfma16(pah, vl, o[dt]);
        o[dt] = mfma16(pal, vh, o[dt]);
      }
    }
    __syncthreads();
  }

  // ---- epilogue: write AO directly as split2 bf16 ----
  float linv[4];
#pragma unroll
  for (int r = 0; r < 4; ++r) linv[r] = 1.f / l_[r];
#pragma unroll
  for (int dt = 0; dt < 8; ++dt)
#pragma unroll
    for (int r = 0; r < 4; ++r) {
      float v = o[dt][r] * linv[r];
      ushortT hi, lo;
      split2(v, hi, lo);
      size_t off = (size_t)(qrow + quad * 4 + r) * HID + h * HD + dt * 16 + m16;
      AOH[off] = hi;
      AOM[off] = lo;
    }
  if (m16 == 0) {
#pragma unroll
    for (int r = 0; r < 4; ++r) {
      Mb[h * SEQ + qrow + quad * 4 + r] = m_[r];   // log2 domain
      Lb[h * SEQ + qrow + quad * 4 + r] = l_[r];
    }
  }
}

// ================= MFMA colsum ============================================
__global__ __launch_bounds__(256, 3) void colsum_mfma_kernel(
    const ushortT* __restrict__ Qh, const ushortT* __restrict__ Qm, const ushortT* __restrict__ Ql,
    const ushortT* __restrict__ Kh, const ushortT* __restrict__ Km, const ushortT* __restrict__ Kl,
    const float* __restrict__ Mb, const float* __restrict__ Lb,
    float* __restrict__ HH) {
  __shared__ ushortT Qs[3][4096];   // [32 q-rows][128 d] per level, subtiled
  __shared__ float ms_s[SEQ];       // whole head m (log2 domain)
  __shared__ float ls_s[SEQ];       // whole head 1/l
  const int tid = threadIdx.x;
  const int w = tid >> 6, l = tid & 63;
  const int m16 = l & 15, quad = l >> 4;
  const int f = blockIdx.x;
  const int xcd = f & 7, g = f >> 3;
  const int h = xcd * 4 + (g >> 5);
  const int kb = g & 31;              // kb=0 is longest -> first
  const int k0 = kb * 64;
  const int kg = k0 + w * 16 + m16;   // this lane's k column

  const ushortT* Qarr[3] = {Qh, Qm, Ql};
  const ushortT* Karr[3] = {Kh, Km, Kl};

  for (int i = tid; i < SEQ; i += 256) {
    ms_s[i] = Mb[h * SEQ + i];
    ls_s[i] = 1.f / Lb[h * SEQ + i];
  }

  // K fragments (wave's 16 k-rows), direct from global, once
  short8 kf[3][4];
  {
    size_t kbase = ((size_t)h * SEQ + k0 + w * 16 + m16) * HD + quad * 8;
#pragma unroll
    for (int lv = 0; lv < 3; ++lv)
#pragma unroll
      for (int ks = 0; ks < 4; ++ks)
        kf[lv][ks] = *(const short8*)&Karr[lv][kbase + ks * 32];
  }

  float acc = 0.f;
  for (int qs = k0; qs < SEQ; qs += 32) {
    // stage Q: 3 lev x 8 chunks = 24, 6 per wave
#pragma unroll
    for (int u = 0; u < 6; ++u) {
      int c = u * 4 + w;
      int lv = c >> 3, cc = c & 7, t2 = cc >> 2, cs = cc & 3;
      const ushortT* g2 = Qarr[lv] + ((size_t)h * SEQ + qs + t2 * 16 + m16) * HD + cs * 32 + quad * 8;
      gload16(g2, &Qs[lv][t2 * 2048 + cs * 512]);
    }
    __syncthreads();

    if (qs + 31 >= k0 + w * 16) {     // skip fully-masked first tiles
#pragma unroll
      for (int t2 = 0; t2 < 2; ++t2) {
        f32x4 sA = {};
#pragma unroll
        for (int ks = 0; ks < 4; ++ks) {
          int off = t2 * 2048 + ks * 512 + quad * 128 + m16 * 8;
          short8 ah = *(const short8*)&Qs[0][off];
          short8 am = *(const short8*)&Qs[1][off];
          short8 al = *(const short8*)&Qs[2][off];
          sA = mfma16(ah, kf[0][ks], sA);
          sA = mfma16(ah, kf[1][ks], sA);
          sA = mfma16(am, kf[0][ks], sA);
          sA = mfma16(am, kf[1][ks], sA);
          sA = mfma16(ah, kf[2][ks], sA);
          sA = mfma16(al, kf[0][ks], sA);
        }
#pragma unroll
        for (int r = 0; r < 4; ++r) {
          int qq = qs + t2 * 16 + quad * 4 + r;   // global q row
          if (qq >= kg)
            acc += exp2f(sA[r] * SCALE2 - ms_s[qq]) * ls_s[qq];
        }
      }
    }
    __syncthreads();
  }

  acc += __shfl_xor(acc, 16);
  acc += __shfl_xor(acc, 32);
  if (l < 16) HH[h * SEQ + k0 + w * 16 + l] = acc;
}

// ================= fp32 fallback flash attention ==========================
__global__ __launch_bounds__(256) void flash_kernel(const float* __restrict__ Q,
                                                    const float* __restrict__ K,
                                                    const float* __restrict__ V,
                                                    float* __restrict__ AO,
                                                    float* __restrict__ Mb,
                                                    float* __restrict__ Lb) {
  __shared__ float Qs[32][136];
  __shared__ float Ks[32][136];
  __shared__ float Vs[32][136];
  __shared__ float Psm[32][33];
  __shared__ float mrow[32], lrow[32], srow[32];
  const int tid = threadIdx.x;
  const int h = blockIdx.y, qt = blockIdx.x;
  const int q0 = qt * 32;
  const float* Qh = Q + (((size_t)h * SEQ + q0) << 7);
  const float* Kh = K + ((size_t)h * SEQ << 7);
  const float* Vh = V + ((size_t)h * SEQ << 7);
  for (int i = tid; i < 1024; i += 256) {
    int row = i >> 5, c4 = (i & 31) * 4;
    *(float4*)&Qs[row][c4] = *(const float4*)&Qh[i * 4];
  }
  if (tid < 32) { mrow[tid] = -INFINITY; lrow[tid] = 0.f; }
  const int r  = tid >> 3;
  const int sl = tid & 7;
  float o_acc[16] = {};
  for (int kt = 0; kt <= qt; ++kt) {
    __syncthreads();
    for (int i = tid; i < 1024; i += 256) {
      int row = i >> 5, c4 = (i & 31) * 4;
      *(float4*)&Ks[row][c4] = *(const float4*)&Kh[(size_t)kt * 4096 + i * 4];
      *(float4*)&Vs[row][c4] = *(const float4*)&Vh[(size_t)kt * 4096 + i * 4];
    }
    __syncthreads();
    float sacc[4] = {};
#pragma unroll 8
    for (int c = 0; c < 128; c += 4) {
      float4 qv = *(const float4*)&Qs[r][c];
#pragma unroll
      for (int j = 0; j < 4; ++j) {
        float4 kv = *(const float4*)&Ks[sl + 8 * j][c];
        sacc[j] = fmaf(qv.x, kv.x, sacc[j]);
        sacc[j] = fmaf(qv.y, kv.y, sacc[j]);
        sacc[j] = fmaf(qv.z, kv.z, sacc[j]);
        sacc[j] = fmaf(qv.w, kv.w, sacc[j]);
      }
    }
    const int qg = q0 + r;
#pragma unroll
    for (int j = 0; j < 4; ++j) {
      int kg = kt * 32 + sl + 8 * j;
      Psm[r][sl + 8 * j] = (kg <= qg) ? (sacc[j] * RSQRT_D) : -INFINITY;
    }
    __syncthreads();
    if (tid < 32) {
      int rr = tid;
      float mold = mrow[rr];
      float mt = mold;
#pragma unroll
      for (int k2 = 0; k2 < 32; ++k2) mt = fmaxf(mt, Psm[rr][k2]);
      float sc = expf(mold - mt);
      float lsv = 0.f;
#pragma unroll
      for (int k2 = 0; k2 < 32; ++k2) {
        float p = expf(Psm[rr][k2] - mt);
        Psm[rr][k2] = p;
        lsv += p;
      }
      mrow[rr] = mt;
      lrow[rr] = lrow[rr] * sc + lsv;
      srow[rr] = sc;
    }
    __syncthreads();
    float sc = srow[r];
#pragma unroll
    for (int d2 = 0; d2 < 16; ++d2) o_acc[d2] *= sc;
#pragma unroll 4
    for (int k2 = 0; k2 < 32; ++k2) {
      float p = Psm[r][k2];
      float4 v0 = *(const float4*)&Vs[k2][sl * 4];
      float4 v1 = *(const float4*)&Vs[k2][sl * 4 + 32];
      float4 v2 = *(const float4*)&Vs[k2][sl * 4 + 64];
      float4 v3 = *(const float4*)&Vs[k2][sl * 4 + 96];
      o_acc[0]  = fmaf(p, v0.x, o_acc[0]);  o_acc[1]  = fmaf(p, v0.y, o_acc[1]);
      o_acc[2]  = fmaf(p, v0.z, o_acc[2]);  o_acc[3]  = fmaf(p, v0.w, o_acc[3]);
      o_acc[4]  = fmaf(p, v1.x, o_acc[4]);  o_acc[5]  = fmaf(p, v1.y, o_acc[5]);
      o_acc[6]  = fmaf(p, v1.z, o_acc[6]);  o_acc[7]  = fmaf(p, v1.w, o_acc[7]);
      o_acc[8]  = fmaf(p, v2.x, o_acc[8]);  o_acc[9]  = fmaf(p, v2.y, o_acc[9]);
      o_acc[10] = fmaf(p, v2.z, o_acc[10]); o_acc[11] = fmaf(p, v2.w, o_acc[11]);
      o_acc[12] = fmaf(p, v3.x, o_acc[12]); o_acc[13] = fmaf(p, v3.y, o_acc[13]);
      o_acc[14] = fmaf(p, v3.z, o_acc[14]); o_acc[15] = fmaf(p, v3.w, o_acc[15]);
    }
  }
  float linv = 1.f / lrow[r];
  int s = q0 + r;
  float* orow = &AO[(size_t)s * HID + h * 128];
#pragma unroll
  for (int m = 0; m < 4; ++m) {
    float4 wv;
    wv.x = o_acc[4 * m + 0] * linv; wv.y = o_acc[4 * m + 1] * linv;
    wv.z = o_acc[4 * m + 2] * linv; wv.w = o_acc[4 * m + 3] * linv;
    *(float4*)&orow[sl * 4 + 32 * m] = wv;
  }
  if (tid < 32) {
    Mb[h * SEQ + q0 + tid] = mrow[tid];
    Lb[h * SEQ + q0 + tid] = lrow[tid];
  }
}

// ================= fp32 fallback colsum ===================================
__global__ __launch_bounds__(256) void colsum_kernel(const float* __restrict__ Q,
                                                     const float* __restrict__ K,
                                                     const float* __restrict__ Mb,
                                                     const float* __restrict__ Lb,
                                                     float* __restrict__ HH) {
  __shared__ float Ks[32][136];
  __shared__ float Qs[32][136];
  __shared__ float ms[32], ls[32];
  __shared__ float part[32][9];
  const int tid = threadIdx.x;
  const int h = blockIdx.y, kt = blockIdx.x;
  const int k0 = kt * 32;
  const float* Kh = K + ((size_t)h * SEQ << 7);
  const float* Qh = Q + ((size_t)h * SEQ << 7);
  for (int i = tid; i < 1024; i += 256) {
    int row = i >> 5, c4 = (i & 31) * 4;
    *(float4*)&Ks[row][c4] = *(const float4*)&Kh[(size_t)k0 * 128 + i * 4];
  }
  const int c = tid >> 3;
  const int qsl = tid & 7;
  const int kg = k0 + c;
  float acc = 0.f;
  for (int qt = kt; qt < NKT; ++qt) {
    __syncthreads();
    for (int i = tid; i < 1024; i += 256) {
      int row = i >> 5, c4 = (i & 31) * 4;
      *(float4*)&Qs[row][c4] = *(const float4*)&Qh[(size_t)qt * 4096 + i * 4];
    }
    if (tid < 32) {
      ms[tid] = Mb[h * SEQ + qt * 32 + tid];
      ls[tid] = 1.f / Lb[h * SEQ + qt * 32 + tid];
    }
    __syncthreads();
    float dacc[4] = {};
#pragma unroll 8
    for (int cc = 0; cc < 128; cc += 4) {
      float4 kv = *(const float4*)&Ks[c][cc];
#pragma unroll
      for (int j = 0; j < 4; ++j) {
        float4 qv = *(const float4*)&Qs[qsl + 8 * j][cc];
        dacc[j] = fmaf(qv.x, kv.x, dacc[j]);
        dacc[j] = fmaf(qv.y, kv.y, dacc[j]);
        dacc[j] = fmaf(qv.z, kv.z, dacc[j]);
        dacc[j] = fmaf(qv.w, kv.w, dacc[j]);
      }
    }
#pragma unroll
    for (int j = 0; j < 4; ++j) {
      int qr = qsl + 8 * j;
      int qg = qt * 32 + qr;
      if (qg >= kg)
        acc += expf(dacc[j] * RSQRT_D - ms[qr]) * ls[qr];
    }
  }
  part[c][qsl] = acc;
  __syncthreads();
  if (qsl == 0) {
    float ssum = 0.f;
#pragma unroll
    for (int t2 = 0; t2 < 8; ++t2) ssum += part[c][t2];
    HH[h * SEQ + k0 + c] = ssum;
  }
}

// ================= top-k: radix-select + compaction + bitonic sort ========
// HH values are sums of softmax probabilities => non-negative floats, whose
// IEEE bit patterns order monotonically as uint32. Select the top-256 set
// (ties -> smallest index, identical to iterative-argmax semantics), then
// sort indices ascending.
__global__ __launch_bounds__(256) void topk_kernel(const float* __restrict__ HH,
                                                   int* __restrict__ keep) {
  __shared__ unsigned int vals[SELN];
  __shared__ unsigned int bins[256];
  __shared__ unsigned int scan[256];
  __shared__ int sel[HHSZ];
  __shared__ unsigned int bc[2];
  const int h = blockIdx.x, tid = threadIdx.x;
  for (int i = tid; i < SELN; i += 256)
    vals[i] = __float_as_uint(HH[h * SEQ + i]);
  __syncthreads();

  // ---- radix select: threshold T (256th largest) + tie count needed ----
  unsigned int prefix = 0;
  int kneed = HHSZ;
#pragma unroll
  for (int round = 0; round < 4; ++round) {
    const int shift = 24 - 8 * round;
    bins[tid] = 0;
    __syncthreads();
    for (int i = tid; i < SELN; i += 256) {
      unsigned int v = vals[i];
      if (round == 0 || (v >> (shift + 8)) == prefix)
        atomicAdd(&bins[(v >> shift) & 255u], 1u);
    }
    __syncthreads();
    // suffix sum: scan[b] = sum_{b' >= b} bins[b']
    scan[tid] = bins[tid];
    __syncthreads();
    for (int off = 1; off < 256; off <<= 1) {
      unsigned int add = (tid + off < 256) ? scan[tid + off] : 0u;
      __syncthreads();
      scan[tid] += add;
      __syncthreads();
    }
    // boundary bin: largest b with suffix[b] >= kneed
    unsigned int above = (tid < 255) ? scan[tid + 1] : 0u;
    if (scan[tid] >= (unsigned int)kneed && above < (unsigned int)kneed) {
      bc[0] = (unsigned int)tid;
      bc[1] = above;
    }
    __syncthreads();
    prefix = (prefix << 8) | bc[0];
    kneed -= (int)bc[1];
    __syncthreads();
  }
  const unsigned int T = prefix;

  // ---- compaction: thread t owns contiguous chunk [6t, 6t+6) ----
  const int base = tid * 6;
  int cGT = 0, cEQ = 0;
#pragma unroll
  for (int j = 0; j < 6; ++j) {
    unsigned int v = vals[base + j];
    cGT += (v > T);
    cEQ += (v == T);
  }
  scan[tid] = (unsigned int)cGT;
  __syncthreads();
  for (int off = 1; off < 256; off <<= 1) {
    unsigned int add = (tid >= off) ? scan[tid - off] : 0u;
    __syncthreads();
    scan[tid] += add;
    __syncthreads();
  }
  const int gtBefore = (int)scan[tid] - cGT;
  const int totalGT = (int)scan[255];
  {
    int pos = gtBefore;
#pragma unroll
    for (int j = 0; j < 6; ++j) {
      unsigned int v = vals[base + j];
      if (v > T) sel[pos++] = base + j;
    }
  }
  __syncthreads();
  scan[tid] = (unsigned int)cEQ;
  __syncthreads();
  for (int off = 1; off < 256; off <<= 1) {
    unsigned int add = (tid >= off) ? scan[tid - off] : 0u;
    __syncthreads();
    scan[tid] += add;
    __syncthreads();
  }
  {
    int pos = (int)scan[tid] - cEQ;   // tie rank in ascending-index order
#pragma unroll
    for (int j = 0; j < 6; ++j) {
      unsigned int v = vals[base + j];
      if (v == T) {
        if (pos < kneed) sel[totalGT + pos] = base + j;
        pos++;
      }
    }
  }
  __syncthreads();

  // ---- bitonic sort of 256 indices, ascending ----
#pragma unroll
  for (int k = 2; k <= 256; k <<= 1) {
    for (int j = k >> 1; j > 0; j >>= 1) {
      int ixj = tid ^ j;
      if (ixj > tid) {
        int a = sel[tid], b = sel[ixj];
        bool up = ((tid & k) == 0);
        if ((a > b) == up) { sel[tid] = b; sel[ixj] = a; }
      }
      __syncthreads();
    }
  }

  keep[h * CACHE + tid] = sel[tid];
  for (int i = tid; i < RECENT; i += 256) keep[h * CACHE + HHSZ + i] = SELN + i;
}

// ================= gather (optionally applies RoPE to K rows) =============
__global__ void gather_kernel(const float* __restrict__ K, const float* __restrict__ V,
                              const float* __restrict__ HH, const int* __restrict__ keep,
                              const int* __restrict__ pos,
                              const float* __restrict__ cosT, const float* __restrict__ sinT,
                              float* __restrict__ k_out, float* __restrict__ v_out,
                              float* __restrict__ hh_out, int rope_k) {
  __shared__ float kr[128];
  const int j = blockIdx.x;
  const int h = blockIdx.y;
  const int d = threadIdx.x;
  const int idx = keep[h * CACHE + j];
  size_t src = (((size_t)h * SEQ + idx) << 7) + d;
  size_t dst = (((size_t)h * CACHE + j) << 7) + d;
  float kv = K[src];
  if (rope_k) {
    kr[d] = kv;
    __syncthreads();
    int p = pos[idx];
    float c = cosT[p * 64 + (d & 63)];
    float sn = sinT[p * 64 + (d & 63)];
    float xo = kr[d ^ 64];
    kv = kv * c + ((d < 64) ? -xo : xo) * sn;
  }
  k_out[dst] = kv;
  v_out[dst] = V[src];
  if (d == 0) hh_out[h * CACHE + j] = HH[h * SEQ + idx];
}

// ================= launch ==================================================
extern "C" void kernel_launch(void* const* d_in, const int* in_sizes, int n_in,
                              void* d_out, int out_size, void* d_ws, size_t ws_size,
                              hipStream_t stream) {
  (void)in_sizes; (void)n_in; (void)out_size;
  const float* hs  = (const float*)d_in[0];
  const int*   pos = (const int*)d_in[1];
  const float* Wq  = (const float*)d_in[2];
  const float* Wk  = (const float*)d_in[3];
  const float* Wv  = (const float*)d_in[4];
  const float* Wo  = (const float*)d_in[5];

  float* out = (float*)d_out;                 // [2048][4096]
  float* khh = out + (size_t)SEQ * HID;       // [32][768][128]
  float* vhh = khh + (size_t)NH * CACHE * HD;
  float* hhk = vhh + (size_t)NH * CACHE * HD; // [32][768]

  char* p = (char*)d_ws;
  auto alloc = [&](size_t bytes) { char* r = p; p += (bytes + 255) & ~(size_t)255; return r; };

  float* Qw   = (float*)alloc((size_t)NH * SEQ * HD * 4);
  float* Kw   = (float*)alloc((size_t)NH * SEQ * HD * 4);
  float* Vw   = (float*)alloc((size_t)NH * SEQ * HD * 4);
  float* AO   = (float*)alloc((size_t)SEQ * HID * 4);   // mfma path: AO bf16 splits live here
  float* Mb   = (float*)alloc((size_t)NH * SEQ * 4);
  float* Lb   = (float*)alloc((size_t)NH * SEQ * 4);
  float* HH   = (float*)alloc((size_t)NH * SEQ * 4);
  float* cosT = (float*)alloc((size_t)SEQ * 64 * 4);
  float* sinT = (float*)alloc((size_t)SEQ * 64 * 4);
  int*   keep = (int*)alloc((size_t)NH * CACHE * 4);
  // bf16 split buffers
  ushortT* hsH = (ushortT*)alloc((size_t)SEQ * HID * 2);
  ushortT* hsM = (ushortT*)alloc((size_t)SEQ * HID * 2);
  ushortT* hsL = (ushortT*)alloc((size_t)SEQ * HID * 2);
  ushortT* WH  = (ushortT*)alloc((size_t)HID * HID * 2);
  ushortT* WM  = (ushortT*)alloc((size_t)HID * HID * 2);
  ushortT* WL  = (ushortT*)alloc((size_t)HID * HID * 2);
  const size_t needed = (size_t)(p - (char*)d_ws);
  const bool use_mfma = ws_size >= needed;

  const dim3 ggrid(32, 16);
  const int n4hs = SEQ * HID / 4;    // 2097152
  const int n4w  = HID * HID / 4;    // 4194304

  rope_tables_kernel<<<SEQ, 64, 0, stream>>>(cosT, sinT);

  if (use_mfma) {
    split3_kernel<<<n4hs / 256, 256, 0, stream>>>(hs, hsH, hsM, hsL, n4hs);
    split3_kernel<<<n4w / 256, 256, 0, stream>>>(Wq, WH, WM, WL, n4w);
    gemm_mfma<3, 1><<<ggrid, 256, 0, stream>>>(hsH, hsM, hsL, WH, WM, WL, Qw);
    split3_kernel<<<n4w / 256, 256, 0, stream>>>(Wk, WH, WM, WL, n4w);
    gemm_mfma<3, 1><<<ggrid, 256, 0, stream>>>(hsH, hsM, hsL, WH, WM, WL, Kw);
    split2_kernel<<<n4w / 256, 256, 0, stream>>>(Wv, WH, WM, n4w);
    gemm_mfma<2, 1><<<ggrid, 256, 0, stream>>>(hsH, hsM, nullptr, WH, WM, nullptr, Vw);

    // RoPE fused into the Q/K split passes (Qw/Kw fp32 stay un-roped;
    // gather applies RoPE to the kept K rows).
    const size_t QKOFF = (size_t)NH * SEQ * HD;   // ushorts
    const int n4qk = NH * SEQ * HD / 4;
    split3_rope_kernel<<<n4qk / 256, 256, 0, stream>>>(Qw, pos, cosT, sinT, WH, WM, WL, n4qk);
    split3_rope_kernel<<<n4qk / 256, 256, 0, stream>>>(Kw, pos, cosT, sinT,
                                                       WH + QKOFF, WM + QKOFF, WL + QKOFF, n4qk);
    split2t_kernel<<<dim3(64, 4, 32), 256, 0, stream>>>(Vw, hsH, hsM);

    ushortT* AOH = (ushortT*)AO;
    ushortT* AOM = AOH + (size_t)SEQ * HID;
    flash_mfma_kernel<<<1024, 256, 0, stream>>>(
        WH, WM, WL, WH + QKOFF, WM + QKOFF, WL + QKOFF, hsH, hsM, AOH, AOM, Mb, Lb);
    colsum_mfma_kernel<<<1024, 256, 0, stream>>>(
        WH, WM, WL, WH + QKOFF, WM + QKOFF, WL + QKOFF, Mb, Lb, HH);

    split2_kernel<<<n4w / 256, 256, 0, stream>>>(Wo, WH, WM, n4w);
    gemm_mfma<2, 0><<<ggrid, 256, 0, stream>>>(AOH, AOM, nullptr, WH, WM, nullptr, out);

    topk_kernel<<<NH, 256, 0, stream>>>(HH, keep);
    gather_kernel<<<dim3(CACHE, NH), 128, 0, stream>>>(Kw, Vw, HH, keep, pos, cosT, sinT,
                                                       khh, vhh, hhk, 1);
  } else {
    gemm_nt<1><<<ggrid, 256, 0, stream>>>(hs, Wq, Qw);
    gemm_nt<1><<<ggrid, 256, 0, stream>>>(hs, Wk, Kw);
    gemm_nt<1><<<ggrid, 256, 0, stream>>>(hs, Wv, Vw);
    rope_apply_kernel<<<dim3(SEQ, NH, 2), 128, 0, stream>>>(Qw, Kw, pos, cosT, sinT);
    flash_kernel<<<dim3(NKT, NH), 256, 0, stream>>>(Qw, Kw, Vw, AO, Mb, Lb);
    colsum_kernel<<<dim3(NKT, NH), 256, 0, stream>>>(Qw, Kw, Mb, Lb, HH);
    gemm_nt<0><<<ggrid, 256, 0, stream>>>(AO, Wo, out);
    topk_kernel<<<NH, 256, 0, stream>>>(HH, keep);
    gather_kernel<<<dim3(CACHE, NH), 128, 0, stream>>>(Kw, Vw, HH, keep, pos, cosT, sinT,
                                                       khh, vhh, hhk, 0);
  }
}

// Round 4
// 2027.587 us; speedup vs baseline: 2.3481x; 1.0677x over previous
//
#include <hip/hip_runtime.h>
#include <hip/hip_bf16.h>
#include <math.h>

#define HID 4096
#define NH 32
#define HD 128
#define SEQ 2048
#define NKT 64
#define HHSZ 256
#define RECENT 512
#define CACHE 768
#define SELN 1536
#define RSQRT_D 0.08838834764831845f
// RSQRT_D * log2(e): scores scaled into log2 domain for exp2-based softmax
#define SCALE2 0.12751749522423355f

typedef unsigned short ushortT;
typedef __attribute__((ext_vector_type(8))) short short8;
typedef __attribute__((ext_vector_type(4))) float f32x4;

// ================= bf16 split helpers =====================================
__device__ __forceinline__ ushortT f2b(float f) {
  union { __hip_bfloat16 h; ushortT u; } v;
  v.h = __float2bfloat16(f);
  return v.u;
}
__device__ __forceinline__ float b2f(ushortT u) {
  union { unsigned int i; float f; } v;
  v.i = ((unsigned int)u) << 16;
  return v.f;
}
__device__ __forceinline__ void split3(float x, ushortT& h, ushortT& m, ushortT& l) {
  h = f2b(x);
  float r = x - b2f(h);
  m = f2b(r);
  float r2 = r - b2f(m);
  l = f2b(r2);
}
__device__ __forceinline__ void split2(float x, ushortT& h, ushortT& l) {
  h = f2b(x);
  l = f2b(x - b2f(h));
}

__global__ __launch_bounds__(256) void split3_kernel(const float* __restrict__ X,
    ushortT* __restrict__ o0, ushortT* __restrict__ o1, ushortT* __restrict__ o2, int n4) {
  int i = blockIdx.x * 256 + threadIdx.x;
  if (i >= n4) return;
  float4 x = ((const float4*)X)[i];
  ushort4 a, b, c;
  split3(x.x, a.x, b.x, c.x);
  split3(x.y, a.y, b.y, c.y);
  split3(x.z, a.z, b.z, c.z);
  split3(x.w, a.w, b.w, c.w);
  ((ushort4*)o0)[i] = a;
  ((ushort4*)o1)[i] = b;
  ((ushort4*)o2)[i] = c;
}
__global__ __launch_bounds__(256) void split2_kernel(const float* __restrict__ X,
    ushortT* __restrict__ o0, ushortT* __restrict__ o1, int n4) {
  int i = blockIdx.x * 256 + threadIdx.x;
  if (i >= n4) return;
  float4 x = ((const float4*)X)[i];
  ushort4 a, b;
  split2(x.x, a.x, b.x);
  split2(x.y, a.y, b.y);
  split2(x.z, a.z, b.z);
  split2(x.w, a.w, b.w);
  ((ushort4*)o0)[i] = a;
  ((ushort4*)o1)[i] = b;
}

// split3 with fused RoPE: X is [h][s][128] fp32 (un-roped); outputs roped splits.
__global__ __launch_bounds__(256) void split3_rope_kernel(const float* __restrict__ X,
    const int* __restrict__ pos, const float* __restrict__ cosT, const float* __restrict__ sinT,
    ushortT* __restrict__ o0, ushortT* __restrict__ o1, ushortT* __restrict__ o2, int n4) {
  int i = blockIdx.x * 256 + threadIdx.x;
  if (i >= n4) return;
  float4 x = ((const float4*)X)[i];
  float4 y = ((const float4*)X)[i ^ 16];   // partner half (d ^ 64)
  int d4 = i & 31;                          // float4 index in 128-elem row
  int row = i >> 5;                         // h*SEQ + s
  int s = row & (SEQ - 1);
  int p = pos[s];
  int d = d4 * 4;
  float4 c = *(const float4*)&cosT[p * 64 + (d & 63)];
  float4 sn = *(const float4*)&sinT[p * 64 + (d & 63)];
  float sg = (d < 64) ? -1.f : 1.f;
  float4 v;
  v.x = x.x * c.x + sg * y.x * sn.x;
  v.y = x.y * c.y + sg * y.y * sn.y;
  v.z = x.z * c.z + sg * y.z * sn.z;
  v.w = x.w * c.w + sg * y.w * sn.w;
  ushort4 a, b, cc;
  split3(v.x, a.x, b.x, cc.x);
  split3(v.y, a.y, b.y, cc.y);
  split3(v.z, a.z, b.z, cc.z);
  split3(v.w, a.w, b.w, cc.w);
  ((ushort4*)o0)[i] = a;
  ((ushort4*)o1)[i] = b;
  ((ushort4*)o2)[i] = cc;
}

// split V [h][s][128] fp32 -> transposed bf16 levels [h][128][2048]
__global__ __launch_bounds__(256) void split2t_kernel(const float* __restrict__ V,
    ushortT* __restrict__ oH, ushortT* __restrict__ oL) {
  __shared__ float T[32][33];
  const int h = blockIdx.z, s0 = blockIdx.x * 32, d0 = blockIdx.y * 32;
  const int t = threadIdx.x;
  {
    int sr = t >> 3, dc = (t & 7) * 4;
    float4 v = *(const float4*)&V[(((size_t)h * SEQ + s0 + sr) << 7) + d0 + dc];
    T[sr][dc + 0] = v.x; T[sr][dc + 1] = v.y;
    T[sr][dc + 2] = v.z; T[sr][dc + 3] = v.w;
  }
  __syncthreads();
  int dr = t >> 3, sc = (t & 7) * 4;
  ushort4 a, b;
  split2(T[sc + 0][dr], a.x, b.x);
  split2(T[sc + 1][dr], a.y, b.y);
  split2(T[sc + 2][dr], a.z, b.z);
  split2(T[sc + 3][dr], a.w, b.w);
  size_t dst = ((size_t)h * HD + d0 + dr) * SEQ + s0 + sc;
  *(ushort4*)&oH[dst] = a;
  *(ushort4*)&oL[dst] = b;
}

// ================= async global->LDS ======================================
__device__ __forceinline__ void gload16(const void* g, void* lds) {
  __builtin_amdgcn_global_load_lds(
      (const __attribute__((address_space(1))) unsigned int*)g,
      (__attribute__((address_space(3))) unsigned int*)lds, 16, 0, 0);
}

__device__ __forceinline__ f32x4 mfma16(short8 a, short8 b, f32x4 c) {
  return __builtin_amdgcn_mfma_f32_16x16x32_bf16(a, b, c, 0, 0, 0);
}

// ================= split-bf16 MFMA GEMM  C = A * B^T ======================
template<int LEV, int MODE>
__global__ __launch_bounds__(256, 2) void gemm_mfma(
    const ushortT* __restrict__ A0, const ushortT* __restrict__ A1, const ushortT* __restrict__ A2,
    const ushortT* __restrict__ B0, const ushortT* __restrict__ B1, const ushortT* __restrict__ B2,
    float* __restrict__ C) {
  __shared__ ushortT As[LEV][4096];
  __shared__ ushortT Bs[LEV][4096];
  const int tid = threadIdx.x;
  const int w = tid >> 6, l = tid & 63;
  const int m16 = l & 15, quad = l >> 4;
  const int wr = w >> 1, wc = w & 1;
  // XCD-chunked swizzle: dispatch round-robins consecutive ids across the 8
  // XCDs, so ids == x (mod 8) land on XCD x. Give each XCD a SQUARE 8x8 panel
  // chunk (rows 8*(x>>2).., cols 8*(x&3)..). Per-XCD distinct bytes drop from
  // the old 2x32 chunk's ~106 MB (entire B!) to ~48 MB, and the 64 resident
  // blocks per XCD march through k in near-lockstep with a per-k-step slice
  // of (8+8 panels)*128*32*2B*LEV ~ 400 KB -> L2-resident -> staging latency
  // ~L2 not ~HBM, so the pre-barrier vmcnt drain shortens.
  const int id = blockIdx.y * 32 + blockIdx.x;          // 0..511
  const int c8 = id & 7, loc = id >> 3;                 // chunk, local 0..63
  const int m0 = ((c8 >> 2) * 8 + (loc & 7)) * 128;
  const int n0 = ((c8 & 3) * 8 + (loc >> 3)) * 128;
  const ushortT* Aarr[3] = {A0, A1, A2};
  const ushortT* Barr[3] = {B0, B1, B2};
  const size_t laneA = (size_t)(m0 + m16) * HID + quad * 8;
  const size_t laneB = (size_t)(n0 + m16) * HID + quad * 8;

  f32x4 acc[4][4] = {};

  for (int k0 = 0; k0 < HID; k0 += 32) {
#pragma unroll
    for (int u = 0; u < LEV * 4; ++u) {
      int t = u * 4 + w;
      int p = t >> 3, q = t & 7;
      const ushortT* g;
      ushortT* s;
      if (p < LEV) {
        g = Aarr[p] + laneA + (size_t)q * 16 * HID + k0;
        s = &As[p][q * 512];
      } else {
        g = Barr[p - LEV] + laneB + (size_t)q * 16 * HID + k0;
        s = &Bs[p - LEV][q * 512];
      }
      gload16(g, s);
    }
    __syncthreads();

    short8 af[LEV][4], bf[LEV][4];
#pragma unroll
    for (int v = 0; v < LEV; ++v)
#pragma unroll
      for (int i = 0; i < 4; ++i) {
        af[v][i] = *(const short8*)&As[v][(wr * 4 + i) * 512 + quad * 128 + m16 * 8];
        bf[v][i] = *(const short8*)&Bs[v][(wc * 4 + i) * 512 + quad * 128 + m16 * 8];
      }
#pragma unroll
    for (int i = 0; i < 4; ++i)
#pragma unroll
      for (int j = 0; j < 4; ++j) {
        acc[i][j] = mfma16(af[0][i], bf[0][j], acc[i][j]);
        acc[i][j] = mfma16(af[0][i], bf[1][j], acc[i][j]);
        acc[i][j] = mfma16(af[1][i], bf[0][j], acc[i][j]);
        if (LEV == 3) {
          acc[i][j] = mfma16(af[1][i], bf[1][j], acc[i][j]);
          acc[i][j] = mfma16(af[0][i], bf[2][j], acc[i][j]);
          acc[i][j] = mfma16(af[2][i], bf[0][j], acc[i][j]);
        }
      }
    __syncthreads();
  }

  const int row0 = m0 + wr * 64;
  const int col0 = n0 + wc * 64;
#pragma unroll
  for (int i = 0; i < 4; ++i)
#pragma unroll
    for (int j = 0; j < 4; ++j) {
#pragma unroll
      for (int r = 0; r < 4; ++r) {
        int row = row0 + i * 16 + quad * 4 + r;
        int col = col0 + j * 16 + m16;
        float v = acc[i][j][r];
        if (MODE == 0) {
          C[(size_t)row * HID + col] = v;
        } else {
          int h = col >> 7, d = col & 127;
          C[(((size_t)h * SEQ + row) << 7) + d] = v;
        }
      }
    }
}

// ================= fp32 fallback GEMM =====================================
template<int MODE>
__global__ __launch_bounds__(256) void gemm_nt(const float* __restrict__ A,
                                               const float* __restrict__ B,
                                               float* __restrict__ C) {
  __shared__ float Asm[16][132];
  __shared__ float Bsm[16][132];
  const int tid = threadIdx.x;
  const int tx = tid & 15, ty = tid >> 4;
  const int m0 = blockIdx.y * 128, n0 = blockIdx.x * 128;
  float acc[8][8] = {};
  for (int k0 = 0; k0 < HID; k0 += 16) {
#pragma unroll
    for (int lp = 0; lp < 2; ++lp) {
      int i = tid + lp * 256;
      int row = i >> 2;
      int col = (i & 3) * 4;
      float4 av = *(const float4*)&A[(size_t)(m0 + row) * HID + k0 + col];
      Asm[col + 0][row] = av.x; Asm[col + 1][row] = av.y;
      Asm[col + 2][row] = av.z; Asm[col + 3][row] = av.w;
      float4 bv = *(const float4*)&B[(size_t)(n0 + row) * HID + k0 + col];
      Bsm[col + 0][row] = bv.x; Bsm[col + 1][row] = bv.y;
      Bsm[col + 2][row] = bv.z; Bsm[col + 3][row] = bv.w;
    }
    __syncthreads();
#pragma unroll
    for (int kk = 0; kk < 16; ++kk) {
      float a[8], b[8];
      *(float4*)&a[0] = *(const float4*)&Asm[kk][ty * 4];
      *(float4*)&a[4] = *(const float4*)&Asm[kk][64 + ty * 4];
      *(float4*)&b[0] = *(const float4*)&Bsm[kk][tx * 4];
      *(float4*)&b[4] = *(const float4*)&Bsm[kk][64 + tx * 4];
#pragma unroll
      for (int i2 = 0; i2 < 8; ++i2)
#pragma unroll
        for (int j2 = 0; j2 < 8; ++j2)
          acc[i2][j2] = fmaf(a[i2], b[j2], acc[i2][j2]);
    }
    __syncthreads();
  }
#pragma unroll
  for (int i2 = 0; i2 < 8; ++i2) {
    int s = m0 + ((i2 < 4) ? (ty * 4 + i2) : (64 + ty * 4 + i2 - 4));
#pragma unroll
    for (int j2 = 0; j2 < 8; ++j2) {
      int o = n0 + ((j2 < 4) ? (tx * 4 + j2) : (64 + tx * 4 + j2 - 4));
      float v = acc[i2][j2];
      if (MODE == 0) {
        C[(size_t)s * HID + o] = v;
      } else {
        int h = o >> 7, d = o & 127;
        C[(((size_t)h * SEQ + s) << 7) + d] = v;
      }
    }
  }
}

// ================= RoPE ====================================================
__global__ void rope_tables_kernel(float* __restrict__ cosT, float* __restrict__ sinT) {
  int t = blockIdx.x;
  int i = threadIdx.x;  // 0..63
  double inv = pow(10000.0, -((double)(2 * i)) / 128.0);
  float ang = (float)t * (float)inv;
  cosT[t * 64 + i] = cosf(ang);
  sinT[t * 64 + i] = sinf(ang);
}

// fallback-path rope (in-place on fp32 Q/K)
__global__ void rope_apply_kernel(float* __restrict__ Q, float* __restrict__ K,
                                  const int* __restrict__ pos,
                                  const float* __restrict__ cosT,
                                  const float* __restrict__ sinT) {
  int d = threadIdx.x;           // 0..127
  int s = blockIdx.x;
  int h = blockIdx.y;
  float* X = blockIdx.z ? K : Q;
  float* row = X + (((size_t)h * SEQ + s) << 7);
  int p = pos[s];
  int i = d & 63;
  float c = cosT[p * 64 + i];
  float sn = sinT[p * 64 + i];
  float x  = row[d];
  float xo = row[(d < 64) ? (d + 64) : (d - 64)];
  float rot = (d < 64) ? -xo : xo;
  __syncthreads();
  row[d] = x * c + rot * sn;
}

// ================= MFMA flash attention ===================================
// Block: 4 waves, 64 q-rows. Softmax in log2 domain (exp2), defer-rescale.
// Grid 1024 flat: swizzled so all heads' biggest q-blocks launch first and
// each XCD co-hosts a 4-head group (K/V L2-resident).
__global__ __launch_bounds__(256, 3) void flash_mfma_kernel(
    const ushortT* __restrict__ Qh, const ushortT* __restrict__ Qm, const ushortT* __restrict__ Ql,
    const ushortT* __restrict__ Kh, const ushortT* __restrict__ Km, const ushortT* __restrict__ Kl,
    const ushortT* __restrict__ VtH, const ushortT* __restrict__ VtL,
    ushortT* __restrict__ AOH, ushortT* __restrict__ AOM,
    float* __restrict__ Mb, float* __restrict__ Lb) {
  __shared__ ushortT Ks[3][4096];   // [32 k-rows][128 d] per level, subtiled
  __shared__ ushortT Vts[2][4096];  // [128 d-rows][32 s] per level, subtiled
  __shared__ ushortT Ps[4][2][512]; // per-wave P tile [16 q][32 k], subtiled
  const int tid = threadIdx.x;
  const int w = tid >> 6, l = tid & 63;
  const int m16 = l & 15, quad = l >> 4;
  const int f = blockIdx.x;
  const int xcd = f & 7, g = f >> 3;
  const int h = xcd * 4 + (g >> 5);   // 4 heads per XCD group
  const int qb = 31 - (g & 31);       // biggest blocks first everywhere
  const int q0 = qb * 64;
  const int qrow = q0 + w * 16;

  const ushortT* Qarr[3] = {Qh, Qm, Ql};
  const ushortT* Karr[3] = {Kh, Km, Kl};
  const ushortT* Varr[2] = {VtH, VtL};

  // Q fragments in registers (wave-private, loaded once)
  short8 qf[3][4];
  {
    size_t qbase = ((size_t)h * SEQ + qrow + m16) * HD + quad * 8;
#pragma unroll
    for (int lv = 0; lv < 3; ++lv)
#pragma unroll
      for (int ks = 0; ks < 4; ++ks)
        qf[lv][ks] = *(const short8*)&Qarr[lv][qbase + ks * 32];
  }

  f32x4 o[8] = {};
  float m_[4] = {-INFINITY, -INFINITY, -INFINITY, -INFINITY};
  float l_[4] = {0.f, 0.f, 0.f, 0.f};

  const int kt_max = 2 * qb + 1;
  const int my_ktmax = 2 * qb + ((w >= 2) ? 1 : 0);   // waves 0,1 skip last tile
  for (int kt = 0; kt <= kt_max; ++kt) {
    // ---- stage K (3 lev) + Vt (2 lev): 40 chunks of 1KB, 10 per wave ----
#pragma unroll
    for (int u = 0; u < 10; ++u) {
      int c = u * 4 + w;
      const ushortT* g2;
      ushortT* s;
      if (c < 24) {
        int lv = c >> 3, cc = c & 7, st = cc >> 2, cs = cc & 3;
        g2 = Karr[lv] + ((size_t)h * SEQ + kt * 32 + st * 16 + m16) * HD + cs * 32 + quad * 8;
        s = &Ks[lv][st * 2048 + cs * 512];
      } else {
        int c2 = c - 24, lv = c2 >> 3, dt = c2 & 7;
        g2 = Varr[lv] + ((size_t)h * HD + dt * 16 + m16) * SEQ + kt * 32 + quad * 8;
        s = &Vts[lv][dt * 512];
      }
      gload16(g2, s);
    }
    __syncthreads();

    if (kt <= my_ktmax) {
      // ---- QK^T: S[16 q][32 k], 6-product split3 ----
      f32x4 sA[2] = {};
#pragma unroll
      for (int t2 = 0; t2 < 2; ++t2)
#pragma unroll
        for (int ks = 0; ks < 4; ++ks) {
          int off = t2 * 2048 + ks * 512 + quad * 128 + m16 * 8;
          short8 bh = *(const short8*)&Ks[0][off];
          short8 bm = *(const short8*)&Ks[1][off];
          short8 bl = *(const short8*)&Ks[2][off];
          sA[t2] = mfma16(qf[0][ks], bh, sA[t2]);
          sA[t2] = mfma16(qf[0][ks], bm, sA[t2]);
          sA[t2] = mfma16(qf[1][ks], bh, sA[t2]);
          sA[t2] = mfma16(qf[1][ks], bm, sA[t2]);
          sA[t2] = mfma16(qf[0][ks], bl, sA[t2]);
          sA[t2] = mfma16(qf[2][ks], bh, sA[t2]);
        }

      // ---- scale (log2 domain) + causal mask (per-wave tight) ----
      const bool need_mask = (kt * 32 + 31 > qrow);
#pragma unroll
      for (int t2 = 0; t2 < 2; ++t2)
#pragma unroll
        for (int r = 0; r < 4; ++r) {
          float v = sA[t2][r] * SCALE2;
          if (need_mask) {
            int kg = kt * 32 + t2 * 16 + m16;
            int qg = qrow + quad * 4 + r;
            if (kg > qg) v = -INFINITY;
          }
          sA[t2][r] = v;
        }

      // ---- online softmax, wave-parallel, defer-rescale ----
      float tmax[4];
#pragma unroll
      for (int r = 0; r < 4; ++r) tmax[r] = fmaxf(sA[0][r], sA[1][r]);
#pragma unroll
      for (int msk = 1; msk <= 8; msk <<= 1)
#pragma unroll
        for (int r = 0; r < 4; ++r)
          tmax[r] = fmaxf(tmax[r], __shfl_xor(tmax[r], msk));

      bool small = true;
#pragma unroll
      for (int r = 0; r < 4; ++r) small = small && (tmax[r] <= m_[r] + 11.0f);
      if (!__all(small)) {
#pragma unroll
        for (int r = 0; r < 4; ++r) {
          float mn = fmaxf(m_[r], tmax[r]);
          float sc = exp2f(m_[r] - mn);
          m_[r] = mn;
          l_[r] *= sc;
#pragma unroll
          for (int dt = 0; dt < 8; ++dt) o[dt][r] *= sc;
        }
      }
      float rs[4];
#pragma unroll
      for (int r = 0; r < 4; ++r) {
        float p0 = exp2f(sA[0][r] - m_[r]);
        float p1 = exp2f(sA[1][r] - m_[r]);
        sA[0][r] = p0; sA[1][r] = p1;
        rs[r] = p0 + p1;
      }
#pragma unroll
      for (int msk = 1; msk <= 8; msk <<= 1)
#pragma unroll
        for (int r = 0; r < 4; ++r) rs[r] += __shfl_xor(rs[r], msk);
#pragma unroll
      for (int r = 0; r < 4; ++r) l_[r] += rs[r];

      // ---- P -> bf16 split2, relayout via wave-private LDS ----
#pragma unroll
      for (int t2 = 0; t2 < 2; ++t2)
#pragma unroll
        for (int r = 0; r < 4; ++r) {
          float p = sA[t2][r];
          ushortT ph = f2b(p);
          ushortT pl = f2b(p - b2f(ph));
          int off = (t2 * 2 + (m16 >> 3)) * 128 + (quad * 4 + r) * 8 + (m16 & 7);
          Ps[w][0][off] = ph;
          Ps[w][1][off] = pl;
        }

      // ---- PV: O += P * V, 3-product split2 ----
      short8 pah = *(const short8*)&Ps[w][0][quad * 128 + m16 * 8];
      short8 pal = *(const short8*)&Ps[w][1][quad * 128 + m16 * 8];
#pragma unroll
      for (int dt = 0; dt < 8; ++dt) {
        int off = dt * 512 + quad * 128 + m16 * 8;
        short8 vh = *(const short8*)&Vts[0][off];
        short8 vl = *(const short8*)&Vts[1][off];
        o[dt] = mfma16(pah, vh, o[dt]);
        o[dt] = mfma16(pah, vl, o[dt]);
        o[dt] = mfma16(pal, vh, o[dt]);
      }
    }
    __syncthreads();
  }

  // ---- epilogue: write AO directly as split2 bf16 ----
  float linv[4];
#pragma unroll
  for (int r = 0; r < 4; ++r) linv[r] = 1.f / l_[r];
#pragma unroll
  for (int dt = 0; dt < 8; ++dt)
#pragma unroll
    for (int r = 0; r < 4; ++r) {
      float v = o[dt][r] * linv[r];
      ushortT hi, lo;
      split2(v, hi, lo);
      size_t off = (size_t)(qrow + quad * 4 + r) * HID + h * HD + dt * 16 + m16;
      AOH[off] = hi;
      AOM[off] = lo;
    }
  if (m16 == 0) {
#pragma unroll
    for (int r = 0; r < 4; ++r) {
      Mb[h * SEQ + qrow + quad * 4 + r] = m_[r];   // log2 domain
      Lb[h * SEQ + qrow + quad * 4 + r] = l_[r];
    }
  }
}

// ================= MFMA colsum ============================================
__global__ __launch_bounds__(256, 3) void colsum_mfma_kernel(
    const ushortT* __restrict__ Qh, const ushortT* __restrict__ Qm, const ushortT* __restrict__ Ql,
    const ushortT* __restrict__ Kh, const ushortT* __restrict__ Km, const ushortT* __restrict__ Kl,
    const float* __restrict__ Mb, const float* __restrict__ Lb,
    float* __restrict__ HH) {
  __shared__ ushortT Qs[3][4096];   // [32 q-rows][128 d] per level, subtiled
  __shared__ float ms_s[SEQ];       // whole head m (log2 domain)
  __shared__ float ls_s[SEQ];       // whole head 1/l
  const int tid = threadIdx.x;
  const int w = tid >> 6, l = tid & 63;
  const int m16 = l & 15, quad = l >> 4;
  const int f = blockIdx.x;
  const int xcd = f & 7, g = f >> 3;
  const int h = xcd * 4 + (g >> 5);
  const int kb = g & 31;              // kb=0 is longest -> first
  const int k0 = kb * 64;
  const int kg = k0 + w * 16 + m16;   // this lane's k column

  const ushortT* Qarr[3] = {Qh, Qm, Ql};
  const ushortT* Karr[3] = {Kh, Km, Kl};

  for (int i = tid; i < SEQ; i += 256) {
    ms_s[i] = Mb[h * SEQ + i];
    ls_s[i] = 1.f / Lb[h * SEQ + i];
  }

  // K fragments (wave's 16 k-rows), direct from global, once
  short8 kf[3][4];
  {
    size_t kbase = ((size_t)h * SEQ + k0 + w * 16 + m16) * HD + quad * 8;
#pragma unroll
    for (int lv = 0; lv < 3; ++lv)
#pragma unroll
      for (int ks = 0; ks < 4; ++ks)
        kf[lv][ks] = *(const short8*)&Karr[lv][kbase + ks * 32];
  }

  float acc = 0.f;
  for (int qs = k0; qs < SEQ; qs += 32) {
    // stage Q: 3 lev x 8 chunks = 24, 6 per wave
#pragma unroll
    for (int u = 0; u < 6; ++u) {
      int c = u * 4 + w;
      int lv = c >> 3, cc = c & 7, t2 = cc >> 2, cs = cc & 3;
      const ushortT* g2 = Qarr[lv] + ((size_t)h * SEQ + qs + t2 * 16 + m16) * HD + cs * 32 + quad * 8;
      gload16(g2, &Qs[lv][t2 * 2048 + cs * 512]);
    }
    __syncthreads();

    if (qs + 31 >= k0 + w * 16) {     // skip fully-masked first tiles
#pragma unroll
      for (int t2 = 0; t2 < 2; ++t2) {
        f32x4 sA = {};
#pragma unroll
        for (int ks = 0; ks < 4; ++ks) {
          int off = t2 * 2048 + ks * 512 + quad * 128 + m16 * 8;
          short8 ah = *(const short8*)&Qs[0][off];
          short8 am = *(const short8*)&Qs[1][off];
          short8 al = *(const short8*)&Qs[2][off];
          sA = mfma16(ah, kf[0][ks], sA);
          sA = mfma16(ah, kf[1][ks], sA);
          sA = mfma16(am, kf[0][ks], sA);
          sA = mfma16(am, kf[1][ks], sA);
          sA = mfma16(ah, kf[2][ks], sA);
          sA = mfma16(al, kf[0][ks], sA);
        }
#pragma unroll
        for (int r = 0; r < 4; ++r) {
          int qq = qs + t2 * 16 + quad * 4 + r;   // global q row
          if (qq >= kg)
            acc += exp2f(sA[r] * SCALE2 - ms_s[qq]) * ls_s[qq];
        }
      }
    }
    __syncthreads();
  }

  acc += __shfl_xor(acc, 16);
  acc += __shfl_xor(acc, 32);
  if (l < 16) HH[h * SEQ + k0 + w * 16 + l] = acc;
}

// ================= fp32 fallback flash attention ==========================
__global__ __launch_bounds__(256) void flash_kernel(const float* __restrict__ Q,
                                                    const float* __restrict__ K,
                                                    const float* __restrict__ V,
                                                    float* __restrict__ AO,
                                                    float* __restrict__ Mb,
                                                    float* __restrict__ Lb) {
  __shared__ float Qs[32][136];
  __shared__ float Ks[32][136];
  __shared__ float Vs[32][136];
  __shared__ float Psm[32][33];
  __shared__ float mrow[32], lrow[32], srow[32];
  const int tid = threadIdx.x;
  const int h = blockIdx.y, qt = blockIdx.x;
  const int q0 = qt * 32;
  const float* Qh = Q + (((size_t)h * SEQ + q0) << 7);
  const float* Kh = K + ((size_t)h * SEQ << 7);
  const float* Vh = V + ((size_t)h * SEQ << 7);
  for (int i = tid; i < 1024; i += 256) {
    int row = i >> 5, c4 = (i & 31) * 4;
    *(float4*)&Qs[row][c4] = *(const float4*)&Qh[i * 4];
  }
  if (tid < 32) { mrow[tid] = -INFINITY; lrow[tid] = 0.f; }
  const int r  = tid >> 3;
  const int sl = tid & 7;
  float o_acc[16] = {};
  for (int kt = 0; kt <= qt; ++kt) {
    __syncthreads();
    for (int i = tid; i < 1024; i += 256) {
      int row = i >> 5, c4 = (i & 31) * 4;
      *(float4*)&Ks[row][c4] = *(const float4*)&Kh[(size_t)kt * 4096 + i * 4];
      *(float4*)&Vs[row][c4] = *(const float4*)&Vh[(size_t)kt * 4096 + i * 4];
    }
    __syncthreads();
    float sacc[4] = {};
#pragma unroll 8
    for (int c = 0; c < 128; c += 4) {
      float4 qv = *(const float4*)&Qs[r][c];
#pragma unroll
      for (int j = 0; j < 4; ++j) {
        float4 kv = *(const float4*)&Ks[sl + 8 * j][c];
        sacc[j] = fmaf(qv.x, kv.x, sacc[j]);
        sacc[j] = fmaf(qv.y, kv.y, sacc[j]);
        sacc[j] = fmaf(qv.z, kv.z, sacc[j]);
        sacc[j] = fmaf(qv.w, kv.w, sacc[j]);
      }
    }
    const int qg = q0 + r;
#pragma unroll
    for (int j = 0; j < 4; ++j) {
      int kg = kt * 32 + sl + 8 * j;
      Psm[r][sl + 8 * j] = (kg <= qg) ? (sacc[j] * RSQRT_D) : -INFINITY;
    }
    __syncthreads();
    if (tid < 32) {
      int rr = tid;
      float mold = mrow[rr];
      float mt = mold;
#pragma unroll
      for (int k2 = 0; k2 < 32; ++k2) mt = fmaxf(mt, Psm[rr][k2]);
      float sc = expf(mold - mt);
      float lsv = 0.f;
#pragma unroll
      for (int k2 = 0; k2 < 32; ++k2) {
        float p = expf(Psm[rr][k2] - mt);
        Psm[rr][k2] = p;
        lsv += p;
      }
      mrow[rr] = mt;
      lrow[rr] = lrow[rr] * sc + lsv;
      srow[rr] = sc;
    }
    __syncthreads();
    float sc = srow[r];
#pragma unroll
    for (int d2 = 0; d2 < 16; ++d2) o_acc[d2] *= sc;
#pragma unroll 4
    for (int k2 = 0; k2 < 32; ++k2) {
      float p = Psm[r][k2];
      float4 v0 = *(const float4*)&Vs[k2][sl * 4];
      float4 v1 = *(const float4*)&Vs[k2][sl * 4 + 32];
      float4 v2 = *(const float4*)&Vs[k2][sl * 4 + 64];
      float4 v3 = *(const float4*)&Vs[k2][sl * 4 + 96];
      o_acc[0]  = fmaf(p, v0.x, o_acc[0]);  o_acc[1]  = fmaf(p, v0.y, o_acc[1]);
      o_acc[2]  = fmaf(p, v0.z, o_acc[2]);  o_acc[3]  = fmaf(p, v0.w, o_acc[3]);
      o_acc[4]  = fmaf(p, v1.x, o_acc[4]);  o_acc[5]  = fmaf(p, v1.y, o_acc[5]);
      o_acc[6]  = fmaf(p, v1.z, o_acc[6]);  o_acc[7]  = fmaf(p, v1.w, o_acc[7]);
      o_acc[8]  = fmaf(p, v2.x, o_acc[8]);  o_acc[9]  = fmaf(p, v2.y, o_acc[9]);
      o_acc[10] = fmaf(p, v2.z, o_acc[10]); o_acc[11] = fmaf(p, v2.w, o_acc[11]);
      o_acc[12] = fmaf(p, v3.x, o_acc[12]); o_acc[13] = fmaf(p, v3.y, o_acc[13]);
      o_acc[14] = fmaf(p, v3.z, o_acc[14]); o_acc[15] = fmaf(p, v3.w, o_acc[15]);
    }
  }
  float linv = 1.f / lrow[r];
  int s = q0 + r;
  float* orow = &AO[(size_t)s * HID + h * 128];
#pragma unroll
  for (int m = 0; m < 4; ++m) {
    float4 wv;
    wv.x = o_acc[4 * m + 0] * linv; wv.y = o_acc[4 * m + 1] * linv;
    wv.z = o_acc[4 * m + 2] * linv; wv.w = o_acc[4 * m + 3] * linv;
    *(float4*)&orow[sl * 4 + 32 * m] = wv;
  }
  if (tid < 32) {
    Mb[h * SEQ + q0 + tid] = mrow[tid];
    Lb[h * SEQ + q0 + tid] = lrow[tid];
  }
}

// ================= fp32 fallback colsum ===================================
__global__ __launch_bounds__(256) void colsum_kernel(const float* __restrict__ Q,
                                                     const float* __restrict__ K,
                                                     const float* __restrict__ Mb,
                                                     const float* __restrict__ Lb,
                                                     float* __restrict__ HH) {
  __shared__ float Ks[32][136];
  __shared__ float Qs[32][136];
  __shared__ float ms[32], ls[32];
  __shared__ float part[32][9];
  const int tid = threadIdx.x;
  const int h = blockIdx.y, kt = blockIdx.x;
  const int k0 = kt * 32;
  const float* Kh = K + ((size_t)h * SEQ << 7);
  const float* Qh = Q + ((size_t)h * SEQ << 7);
  for (int i = tid; i < 1024; i += 256) {
    int row = i >> 5, c4 = (i & 31) * 4;
    *(float4*)&Ks[row][c4] = *(const float4*)&Kh[(size_t)k0 * 128 + i * 4];
  }
  const int c = tid >> 3;
  const int qsl = tid & 7;
  const int kg = k0 + c;
  float acc = 0.f;
  for (int qt = kt; qt < NKT; ++qt) {
    __syncthreads();
    for (int i = tid; i < 1024; i += 256) {
      int row = i >> 5, c4 = (i & 31) * 4;
      *(float4*)&Qs[row][c4] = *(const float4*)&Qh[(size_t)qt * 4096 + i * 4];
    }
    if (tid < 32) {
      ms[tid] = Mb[h * SEQ + qt * 32 + tid];
      ls[tid] = 1.f / Lb[h * SEQ + qt * 32 + tid];
    }
    __syncthreads();
    float dacc[4] = {};
#pragma unroll 8
    for (int cc = 0; cc < 128; cc += 4) {
      float4 kv = *(const float4*)&Ks[c][cc];
#pragma unroll
      for (int j = 0; j < 4; ++j) {
        float4 qv = *(const float4*)&Qs[qsl + 8 * j][cc];
        dacc[j] = fmaf(qv.x, kv.x, dacc[j]);
        dacc[j] = fmaf(qv.y, kv.y, dacc[j]);
        dacc[j] = fmaf(qv.z, kv.z, dacc[j]);
        dacc[j] = fmaf(qv.w, kv.w, dacc[j]);
      }
    }
#pragma unroll
    for (int j = 0; j < 4; ++j) {
      int qr = qsl + 8 * j;
      int qg = qt * 32 + qr;
      if (qg >= kg)
        acc += expf(dacc[j] * RSQRT_D - ms[qr]) * ls[qr];
    }
  }
  part[c][qsl] = acc;
  __syncthreads();
  if (qsl == 0) {
    float ssum = 0.f;
#pragma unroll
    for (int t2 = 0; t2 < 8; ++t2) ssum += part[c][t2];
    HH[h * SEQ + k0 + c] = ssum;
  }
}

// ================= top-k: radix-select + compaction + bitonic sort ========
// HH values are sums of softmax probabilities => non-negative floats, whose
// IEEE bit patterns order monotonically as uint32. Select the top-256 set
// (ties -> smallest index, identical to iterative-argmax semantics), then
// sort indices ascending.
__global__ __launch_bounds__(256) void topk_kernel(const float* __restrict__ HH,
                                                   int* __restrict__ keep) {
  __shared__ unsigned int vals[SELN];
  __shared__ unsigned int bins[256];
  __shared__ unsigned int scan[256];
  __shared__ int sel[HHSZ];
  __shared__ unsigned int bc[2];
  const int h = blockIdx.x, tid = threadIdx.x;
  for (int i = tid; i < SELN; i += 256)
    vals[i] = __float_as_uint(HH[h * SEQ + i]);
  __syncthreads();

  // ---- radix select: threshold T (256th largest) + tie count needed ----
  unsigned int prefix = 0;
  int kneed = HHSZ;
#pragma unroll
  for (int round = 0; round < 4; ++round) {
    const int shift = 24 - 8 * round;
    bins[tid] = 0;
    __syncthreads();
    for (int i = tid; i < SELN; i += 256) {
      unsigned int v = vals[i];
      if (round == 0 || (v >> (shift + 8)) == prefix)
        atomicAdd(&bins[(v >> shift) & 255u], 1u);
    }
    __syncthreads();
    // suffix sum: scan[b] = sum_{b' >= b} bins[b']
    scan[tid] = bins[tid];
    __syncthreads();
    for (int off = 1; off < 256; off <<= 1) {
      unsigned int add = (tid + off < 256) ? scan[tid + off] : 0u;
      __syncthreads();
      scan[tid] += add;
      __syncthreads();
    }
    // boundary bin: largest b with suffix[b] >= kneed
    unsigned int above = (tid < 255) ? scan[tid + 1] : 0u;
    if (scan[tid] >= (unsigned int)kneed && above < (unsigned int)kneed) {
      bc[0] = (unsigned int)tid;
      bc[1] = above;
    }
    __syncthreads();
    prefix = (prefix << 8) | bc[0];
    kneed -= (int)bc[1];
    __syncthreads();
  }
  const unsigned int T = prefix;

  // ---- compaction: thread t owns contiguous chunk [6t, 6t+6) ----
  const int base = tid * 6;
  int cGT = 0, cEQ = 0;
#pragma unroll
  for (int j = 0; j < 6; ++j) {
    unsigned int v = vals[base + j];
    cGT += (v > T);
    cEQ += (v == T);
  }
  scan[tid] = (unsigned int)cGT;
  __syncthreads();
  for (int off = 1; off < 256; off <<= 1) {
    unsigned int add = (tid >= off) ? scan[tid - off] : 0u;
    __syncthreads();
    scan[tid] += add;
    __syncthreads();
  }
  const int gtBefore = (int)scan[tid] - cGT;
  const int totalGT = (int)scan[255];
  {
    int pos = gtBefore;
#pragma unroll
    for (int j = 0; j < 6; ++j) {
      unsigned int v = vals[base + j];
      if (v > T) sel[pos++] = base + j;
    }
  }
  __syncthreads();
  scan[tid] = (unsigned int)cEQ;
  __syncthreads();
  for (int off = 1; off < 256; off <<= 1) {
    unsigned int add = (tid >= off) ? scan[tid - off] : 0u;
    __syncthreads();
    scan[tid] += add;
    __syncthreads();
  }
  {
    int pos = (int)scan[tid] - cEQ;   // tie rank in ascending-index order
#pragma unroll
    for (int j = 0; j < 6; ++j) {
      unsigned int v = vals[base + j];
      if (v == T) {
        if (pos < kneed) sel[totalGT + pos] = base + j;
        pos++;
      }
    }
  }
  __syncthreads();

  // ---- bitonic sort of 256 indices, ascending ----
#pragma unroll
  for (int k = 2; k <= 256; k <<= 1) {
    for (int j = k >> 1; j > 0; j >>= 1) {
      int ixj = tid ^ j;
      if (ixj > tid) {
        int a = sel[tid], b = sel[ixj];
        bool up = ((tid & k) == 0);
        if ((a > b) == up) { sel[tid] = b; sel[ixj] = a; }
      }
      __syncthreads();
    }
  }

  keep[h * CACHE + tid] = sel[tid];
  for (int i = tid; i < RECENT; i += 256) keep[h * CACHE + HHSZ + i] = SELN + i;
}

// ================= gather (optionally applies RoPE to K rows) =============
__global__ void gather_kernel(const float* __restrict__ K, const float* __restrict__ V,
                              const float* __restrict__ HH, const int* __restrict__ keep,
                              const int* __restrict__ pos,
                              const float* __restrict__ cosT, const float* __restrict__ sinT,
                              float* __restrict__ k_out, float* __restrict__ v_out,
                              float* __restrict__ hh_out, int rope_k) {
  __shared__ float kr[128];
  const int j = blockIdx.x;
  const int h = blockIdx.y;
  const int d = threadIdx.x;
  const int idx = keep[h * CACHE + j];
  size_t src = (((size_t)h * SEQ + idx) << 7) + d;
  size_t dst = (((size_t)h * CACHE + j) << 7) + d;
  float kv = K[src];
  if (rope_k) {
    kr[d] = kv;
    __syncthreads();
    int p = pos[idx];
    float c = cosT[p * 64 + (d & 63)];
    float sn = sinT[p * 64 + (d & 63)];
    float xo = kr[d ^ 64];
    kv = kv * c + ((d < 64) ? -xo : xo) * sn;
  }
  k_out[dst] = kv;
  v_out[dst] = V[src];
  if (d == 0) hh_out[h * CACHE + j] = HH[h * SEQ + idx];
}

// ================= launch ==================================================
extern "C" void kernel_launch(void* const* d_in, const int* in_sizes, int n_in,
                              void* d_out, int out_size, void* d_ws, size_t ws_size,
                              hipStream_t stream) {
  (void)in_sizes; (void)n_in; (void)out_size;
  const float* hs  = (const float*)d_in[0];
  const int*   pos = (const int*)d_in[1];
  const float* Wq  = (const float*)d_in[2];
  const float* Wk  = (const float*)d_in[3];
  const float* Wv  = (const float*)d_in[4];
  const float* Wo  = (const float*)d_in[5];

  float* out = (float*)d_out;                 // [2048][4096]
  float* khh = out + (size_t)SEQ * HID;       // [32][768][128]
  float* vhh = khh + (size_t)NH * CACHE * HD;
  float* hhk = vhh + (size_t)NH * CACHE * HD; // [32][768]

  char* p = (char*)d_ws;
  auto alloc = [&](size_t bytes) { char* r = p; p += (bytes + 255) & ~(size_t)255; return r; };

  float* Qw   = (float*)alloc((size_t)NH * SEQ * HD * 4);
  float* Kw   = (float*)alloc((size_t)NH * SEQ * HD * 4);
  float* Vw   = (float*)alloc((size_t)NH * SEQ * HD * 4);
  float* AO   = (float*)alloc((size_t)SEQ * HID * 4);   // mfma path: AO bf16 splits live here
  float* Mb   = (float*)alloc((size_t)NH * SEQ * 4);
  float* Lb   = (float*)alloc((size_t)NH * SEQ * 4);
  float* HH   = (float*)alloc((size_t)NH * SEQ * 4);
  float* cosT = (float*)alloc((size_t)SEQ * 64 * 4);
  float* sinT = (float*)alloc((size_t)SEQ * 64 * 4);
  int*   keep = (int*)alloc((size_t)NH * CACHE * 4);
  // bf16 split buffers
  ushortT* hsH = (ushortT*)alloc((size_t)SEQ * HID * 2);
  ushortT* hsM = (ushortT*)alloc((size_t)SEQ * HID * 2);
  ushortT* hsL = (ushortT*)alloc((size_t)SEQ * HID * 2);
  ushortT* WH  = (ushortT*)alloc((size_t)HID * HID * 2);
  ushortT* WM  = (ushortT*)alloc((size_t)HID * HID * 2);
  ushortT* WL  = (ushortT*)alloc((size_t)HID * HID * 2);
  const size_t needed = (size_t)(p - (char*)d_ws);
  const bool use_mfma = ws_size >= needed;

  const dim3 ggrid(32, 16);
  const int n4hs = SEQ * HID / 4;    // 2097152
  const int n4w  = HID * HID / 4;    // 4194304

  rope_tables_kernel<<<SEQ, 64, 0, stream>>>(cosT, sinT);

  if (use_mfma) {
    split3_kernel<<<n4hs / 256, 256, 0, stream>>>(hs, hsH, hsM, hsL, n4hs);
    split3_kernel<<<n4w / 256, 256, 0, stream>>>(Wq, WH, WM, WL, n4w);
    gemm_mfma<3, 1><<<ggrid, 256, 0, stream>>>(hsH, hsM, hsL, WH, WM, WL, Qw);
    split3_kernel<<<n4w / 256, 256, 0, stream>>>(Wk, WH, WM, WL, n4w);
    gemm_mfma<3, 1><<<ggrid, 256, 0, stream>>>(hsH, hsM, hsL, WH, WM, WL, Kw);
    split2_kernel<<<n4w / 256, 256, 0, stream>>>(Wv, WH, WM, n4w);
    gemm_mfma<2, 1><<<ggrid, 256, 0, stream>>>(hsH, hsM, nullptr, WH, WM, nullptr, Vw);

    // RoPE fused into the Q/K split passes (Qw/Kw fp32 stay un-roped;
    // gather applies RoPE to the kept K rows).
    const size_t QKOFF = (size_t)NH * SEQ * HD;   // ushorts
    const int n4qk = NH * SEQ * HD / 4;
    split3_rope_kernel<<<n4qk / 256, 256, 0, stream>>>(Qw, pos, cosT, sinT, WH, WM, WL, n4qk);
    split3_rope_kernel<<<n4qk / 256, 256, 0, stream>>>(Kw, pos, cosT, sinT,
                                                       WH + QKOFF, WM + QKOFF, WL + QKOFF, n4qk);
    split2t_kernel<<<dim3(64, 4, 32), 256, 0, stream>>>(Vw, hsH, hsM);

    ushortT* AOH = (ushortT*)AO;
    ushortT* AOM = AOH + (size_t)SEQ * HID;
    flash_mfma_kernel<<<1024, 256, 0, stream>>>(
        WH, WM, WL, WH + QKOFF, WM + QKOFF, WL + QKOFF, hsH, hsM, AOH, AOM, Mb, Lb);
    colsum_mfma_kernel<<<1024, 256, 0, stream>>>(
        WH, WM, WL, WH + QKOFF, WM + QKOFF, WL + QKOFF, Mb, Lb, HH);

    split2_kernel<<<n4w / 256, 256, 0, stream>>>(Wo, WH, WM, n4w);
    gemm_mfma<2, 0><<<ggrid, 256, 0, stream>>>(AOH, AOM, nullptr, WH, WM, nullptr, out);

    topk_kernel<<<NH, 256, 0, stream>>>(HH, keep);
    gather_kernel<<<dim3(CACHE, NH), 128, 0, stream>>>(Kw, Vw, HH, keep, pos, cosT, sinT,
                                                       khh, vhh, hhk, 1);
  } else {
    gemm_nt<1><<<ggrid, 256, 0, stream>>>(hs, Wq, Qw);
    gemm_nt<1><<<ggrid, 256, 0, stream>>>(hs, Wk, Kw);
    gemm_nt<1><<<ggrid, 256, 0, stream>>>(hs, Wv, Vw);
    rope_apply_kernel<<<dim3(SEQ, NH, 2), 128, 0, stream>>>(Qw, Kw, pos, cosT, sinT);
    flash_kernel<<<dim3(NKT, NH), 256, 0, stream>>>(Qw, Kw, Vw, AO, Mb, Lb);
    colsum_kernel<<<dim3(NKT, NH), 256, 0, stream>>>(Qw, Kw, Mb, Lb, HH);
    gemm_nt<0><<<ggrid, 256, 0, stream>>>(AO, Wo, out);
    topk_kernel<<<NH, 256, 0, stream>>>(HH, keep);
    gather_kernel<<<dim3(CACHE, NH), 128, 0, stream>>>(Kw, Vw, HH, keep, pos, cosT, sinT,
                                                       khh, vhh, hhk, 0);
  }
}